// Round 2
// baseline (1055.466 us; speedup 1.0000x reference)
//
#include <hip/hip_runtime.h>

#define T_TOK 1024
#define H_DIM 2048
#define I_DIM 7168
#define E_NUM 8
#define R_RANK 159
#define RP 160
#define P_PAIRS 2048

typedef __attribute__((ext_vector_type(8))) short short8;
typedef __attribute__((ext_vector_type(4))) float f32x4;

__device__ __forceinline__ ushort f2b(float f) {
  uint u = __float_as_uint(f);
  uint r = (u + 0x7FFFu + ((u >> 16) & 1u)) >> 16;
  return (ushort)r;
}
__device__ __forceinline__ float b2f(ushort u) {
  return __uint_as_float(((uint)u) << 16);
}
__device__ __forceinline__ short8 pack8(float4 a, float4 b) {
  short8 o;
  o[0] = (short)f2b(a.x); o[1] = (short)f2b(a.y); o[2] = (short)f2b(a.z); o[3] = (short)f2b(a.w);
  o[4] = (short)f2b(b.x); o[5] = (short)f2b(b.y); o[6] = (short)f2b(b.z); o[7] = (short)f2b(b.w);
  return o;
}

// ---------------- router ----------------
__global__ __launch_bounds__(256) void router_kernel(
    const float* __restrict__ x, const float* __restrict__ gw,
    float* __restrict__ logits, float* __restrict__ comb,
    int* __restrict__ sel_e, int* __restrict__ cnt) {
  int wave = threadIdx.x >> 6, lane = threadIdx.x & 63;
  int t = blockIdx.x * 4 + wave;
  const float* xr = x + (long)t * H_DIM;
  float acc[8] = {0.f,0.f,0.f,0.f,0.f,0.f,0.f,0.f};
  for (int h = lane * 4; h < H_DIM; h += 256) {
    const float4 xv = *(const float4*)&xr[h];
#pragma unroll
    for (int e = 0; e < 8; ++e) {
      const float4 gv = *(const float4*)&gw[e * H_DIM + h];
      acc[e] += xv.x * gv.x + xv.y * gv.y + xv.z * gv.z + xv.w * gv.w;
    }
  }
#pragma unroll
  for (int off = 32; off > 0; off >>= 1)
#pragma unroll
    for (int e = 0; e < 8; ++e) acc[e] += __shfl_down(acc[e], off);
  if (lane == 0) {
#pragma unroll
    for (int e = 0; e < 8; ++e) logits[(long)t * 8 + e] = acc[e];
    int i0 = 0;
    for (int e = 1; e < 8; ++e) if (acc[e] > acc[i0]) i0 = e;
    int i1 = (i0 == 0) ? 1 : 0;
    for (int e = 0; e < 8; ++e) if (e != i0 && acc[e] > acc[i1]) i1 = e;
    float ee = __expf(acc[i1] - acc[i0]);
    float w0 = 1.f / (1.f + ee), w1 = ee / (1.f + ee);
    for (int e = 0; e < 8; ++e) comb[t * 8 + e] = 0.f;
    comb[t * 8 + i0] = w0;
    comb[t * 8 + i1] = w1;
    sel_e[t * 2] = i0;
    sel_e[t * 2 + 1] = i1;
    atomicAdd(&cnt[i0], 1);
    atomicAdd(&cnt[i1], 1);
  }
}

__global__ void init_kernel(int* cnt, int* cursor) {
  int i = threadIdx.x;
  if (i < 8) { cnt[i] = 0; cursor[i] = 0; }
}

__global__ void scan_kernel(const int* cnt, int* seg) {
  if (threadIdx.x == 0) {
    int s = 0;
    for (int e = 0; e < 8; ++e) { seg[e] = s; s += cnt[e]; }
    seg[8] = s;
  }
}

__global__ void assign_kernel(const int* __restrict__ sel_e, const float* __restrict__ comb,
                              const int* __restrict__ seg, int* __restrict__ cursor,
                              int* __restrict__ tok, float* __restrict__ wrow,
                              int* __restrict__ row_of) {
  int t = blockIdx.x * blockDim.x + threadIdx.x;
  if (t >= T_TOK) return;
  for (int k = 0; k < 2; ++k) {
    int e = sel_e[t * 2 + k];
    int pos = atomicAdd(&cursor[e], 1);
    int row = seg[e] + pos;
    tok[row] = t;
    wrow[row] = comb[t * 8 + e];
    row_of[t * 2 + k] = row;
  }
}

// [rows,159] f32 -> [rows,160] bf16 (zero pad last col)
__global__ void padcast_kernel(const float* __restrict__ src, ushort* __restrict__ dst, long rows) {
  long total = rows * RP;
  long idx = (long)blockIdx.x * blockDim.x + threadIdx.x;
  long stride = (long)gridDim.x * blockDim.x;
  for (long i = idx; i < total; i += stride) {
    int r = (int)(i % RP);
    long row = i / RP;
    dst[i] = (r < R_RANK) ? f2b(src[row * R_RANK + r]) : (ushort)0;
  }
}

// hc[t,i] = hmid[row0,i] + hmid[row1,i]   (bf16)
__global__ void hcomb_kernel(const ushort* __restrict__ hmid, const int* __restrict__ row_of,
                             ushort* __restrict__ hc) {
  long idx = (long)blockIdx.x * blockDim.x + threadIdx.x;
  long total = (long)T_TOK * I_DIM / 8;
  if (idx >= total) return;
  long i = idx * 8;
  int t = (int)(i / I_DIM);
  int col = (int)(i % I_DIM);
  int r0 = row_of[t * 2], r1 = row_of[t * 2 + 1];
  const short8 a = *(const short8*)&hmid[(long)r0 * I_DIM + col];
  const short8 b = *(const short8*)&hmid[(long)r1 * I_DIM + col];
  short8 o;
#pragma unroll
  for (int j = 0; j < 8; ++j)
    o[j] = (short)f2b(b2f((ushort)a[j]) + b2f((ushort)b[j]));
  *(short8*)&hc[i] = o;
}

// out[t,h] += delta[row0,h] + delta[row1,h]  (delta bf16)
__global__ void finalfix_kernel(float* __restrict__ out, const ushort* __restrict__ delta,
                                const int* __restrict__ row_of) {
  long idx = (long)blockIdx.x * blockDim.x + threadIdx.x;
  long total = (long)T_TOK * H_DIM / 4;
  if (idx >= total) return;
  long i = idx * 4;
  int t = (int)(i / H_DIM);
  int col = (int)(i % H_DIM);
  int r0 = row_of[t * 2], r1 = row_of[t * 2 + 1];
  float4 d = *(float4*)&out[i];
  d.x += b2f(delta[(long)r0 * H_DIM + col + 0]) + b2f(delta[(long)r1 * H_DIM + col + 0]);
  d.y += b2f(delta[(long)r0 * H_DIM + col + 1]) + b2f(delta[(long)r1 * H_DIM + col + 1]);
  d.z += b2f(delta[(long)r0 * H_DIM + col + 2]) + b2f(delta[(long)r1 * H_DIM + col + 2]);
  d.w += b2f(delta[(long)r0 * H_DIM + col + 3]) + b2f(delta[(long)r1 * H_DIM + col + 3]);
  *(float4*)&out[i] = d;
}

// ---------------- general GEMM: C[M,N] = A[M,K] @ B[N,K]^T ----------------
// AF32/BF32: source dtype f32 (cast-in-staging) vs bf16 (global_load_lds).
// CBF16: write bf16 (else f32). PEREXP: per-expert segment via blockIdx.z.
// AMAP: A row indirection through tok[].
// Store cols c<N get acc, N<=c<Npad get 0 (K-padding for downstream GEMMs).
template <int AF32, int BF32, int CBF16, int PEREXP, int AMAP>
__global__ __launch_bounds__(256) void gemm_f(
    const void* __restrict__ Ap, int lda,
    const void* __restrict__ Bp, int ldb, long Bstride,
    int M, int N, int K, int Npad,
    float* __restrict__ Cf, ushort* __restrict__ Cb, int ldc,
    const int* __restrict__ tok, const int* __restrict__ seg, const int* __restrict__ cnt) {
  __shared__ ushort As[128 * 32];
  __shared__ ushort Bs[128 * 32];
  const float* Af = (const float*)Ap;
  const ushort* Ab = (const ushort*)Ap;
  const float* Bf = (const float*)Bp;
  const ushort* Bb = (const ushort*)Bp;
  const int* amap = tok;
  if (PEREXP) {
    int e = blockIdx.z;
    int m0 = seg[e];
    M = cnt[e];
    if ((int)(blockIdx.y * 128) >= M) return;
    if (AMAP) {
      amap = tok + m0;
    } else {
      if (AF32) Af += (long)m0 * lda; else Ab += (long)m0 * lda;
    }
    if (BF32) Bf += (long)e * Bstride; else Bb += (long)e * Bstride;
    if (CBF16) Cb += (long)m0 * ldc; else Cf += (long)m0 * ldc;
  }
  const int tid = threadIdx.x;
  const int lane = tid & 63, wave = tid >> 6;
  const int wm = (wave >> 1) * 64, wn = (wave & 1) * 64;
  const int row0 = blockIdx.y * 128, col0 = blockIdx.x * 128;
  const int sub_r = tid >> 2;
  const int sub_c = (tid & 3) * 8;

  const float* afrow[2]; const ushort* abrow[2];
  const float* bfrow[2]; const ushort* bbrow[2];
#pragma unroll
  for (int p = 0; p < 2; ++p) {
    int r = row0 + p * 64 + sub_r; if (r > M - 1) r = M - 1;
    if (AMAP) r = amap[r];
    if (AF32) afrow[p] = Af + (long)r * lda + sub_c;
    else      abrow[p] = Ab + (long)r * lda + sub_c;
    int q = col0 + p * 64 + sub_r; if (q > N - 1) q = N - 1;
    if (BF32) bfrow[p] = Bf + (long)q * ldb + sub_c;
    else      bbrow[p] = Bb + (long)q * ldb + sub_c;
  }

  f32x4 acc[4][4] = {};

  for (int k0 = 0; k0 < K; k0 += 32) {
    float4 a0[2], a1[2], b0[2], b1[2];
    if (AF32) {
#pragma unroll
      for (int p = 0; p < 2; ++p) {
        a0[p] = *(const float4*)(afrow[p] + k0);
        a1[p] = *(const float4*)(afrow[p] + k0 + 4);
      }
    }
    if (BF32) {
#pragma unroll
      for (int p = 0; p < 2; ++p) {
        b0[p] = *(const float4*)(bfrow[p] + k0);
        b1[p] = *(const float4*)(bfrow[p] + k0 + 4);
      }
    }
    __syncthreads();
#pragma unroll
    for (int p = 0; p < 2; ++p) {
      if (AF32) {
        *(short8*)&As[(p * 256 + tid) * 8] = pack8(a0[p], a1[p]);
      } else {
        __builtin_amdgcn_global_load_lds((const __attribute__((address_space(1))) void*)(abrow[p] + k0),
                                         (__attribute__((address_space(3))) void*)&As[(p * 256 + tid) * 8],
                                         16, 0, 0);
      }
      if (BF32) {
        *(short8*)&Bs[(p * 256 + tid) * 8] = pack8(b0[p], b1[p]);
      } else {
        __builtin_amdgcn_global_load_lds((const __attribute__((address_space(1))) void*)(bbrow[p] + k0),
                                         (__attribute__((address_space(3))) void*)&Bs[(p * 256 + tid) * 8],
                                         16, 0, 0);
      }
    }
    __syncthreads();

    short8 av[4], bv[4];
#pragma unroll
    for (int mi = 0; mi < 4; ++mi)
      av[mi] = *(const short8*)&As[(wm + mi * 16 + (lane & 15)) * 32 + (lane >> 4) * 8];
#pragma unroll
    for (int ni = 0; ni < 4; ++ni)
      bv[ni] = *(const short8*)&Bs[(wn + ni * 16 + (lane & 15)) * 32 + (lane >> 4) * 8];
#pragma unroll
    for (int mi = 0; mi < 4; ++mi)
#pragma unroll
      for (int ni = 0; ni < 4; ++ni)
        acc[mi][ni] = __builtin_amdgcn_mfma_f32_16x16x32_bf16(av[mi], bv[ni], acc[mi][ni], 0, 0, 0);
  }

  const int er = (lane >> 4) * 4;
  const int ec = lane & 15;
#pragma unroll
  for (int mi = 0; mi < 4; ++mi)
#pragma unroll
    for (int ni = 0; ni < 4; ++ni)
#pragma unroll
      for (int j = 0; j < 4; ++j) {
        int r = row0 + wm + mi * 16 + er + j;
        int c = col0 + wn + ni * 16 + ec;
        if (r < M && c < Npad) {
          float v = (c < N) ? acc[mi][ni][j] : 0.f;
          if (CBF16) Cb[(long)r * ldc + c] = f2b(v);
          else       Cf[(long)r * ldc + c] = v;
        }
      }
}

// ---------------- fused dual GEMM: gate/up expansion + silu + weight ----------------
__global__ __launch_bounds__(256) void gemm_hmid(
    const ushort* __restrict__ t1g, const ushort* __restrict__ t3g,   // [2048,160]
    const ushort* __restrict__ du1b, const ushort* __restrict__ du3b, // [8,7168,160]
    const ushort* __restrict__ bgate, const ushort* __restrict__ bup, // [1024,7168]
    const int* __restrict__ tok, const float* __restrict__ wrow,
    const int* __restrict__ seg, const int* __restrict__ cnt,
    ushort* __restrict__ hmid) {                                      // [2048,7168]
  __shared__ ushort As1[128 * 32], As3[128 * 32];
  __shared__ ushort Bs1[128 * 32], Bs3[128 * 32];
  int e = blockIdx.z;
  int m0 = seg[e], M = cnt[e];
  if ((int)(blockIdx.y * 128) >= M) return;
  const ushort* A1 = t1g + (long)m0 * RP;
  const ushort* A3 = t3g + (long)m0 * RP;
  const ushort* B1 = du1b + (long)e * I_DIM * RP;
  const ushort* B3 = du3b + (long)e * I_DIM * RP;
  tok += m0; wrow += m0;
  ushort* H = hmid + (long)m0 * I_DIM;

  const int tid = threadIdx.x;
  const int lane = tid & 63, wave = tid >> 6;
  const int wm = (wave >> 1) * 64, wn = (wave & 1) * 64;
  const int row0 = blockIdx.y * 128, col0 = blockIdx.x * 128;
  const int sub_r = tid >> 2;
  const int sub_c = (tid & 3) * 8;

  const ushort *a1r[2], *a3r[2], *b1r[2], *b3r[2];
#pragma unroll
  for (int p = 0; p < 2; ++p) {
    int r = row0 + p * 64 + sub_r; if (r > M - 1) r = M - 1;
    a1r[p] = A1 + (long)r * RP + sub_c;
    a3r[p] = A3 + (long)r * RP + sub_c;
    int q = col0 + p * 64 + sub_r; if (q > I_DIM - 1) q = I_DIM - 1;
    b1r[p] = B1 + (long)q * RP + sub_c;
    b3r[p] = B3 + (long)q * RP + sub_c;
  }

  f32x4 acc1[4][4] = {}, acc3[4][4] = {};

  for (int k0 = 0; k0 < RP; k0 += 32) {
    __syncthreads();
#pragma unroll
    for (int p = 0; p < 2; ++p) {
      __builtin_amdgcn_global_load_lds((const __attribute__((address_space(1))) void*)(a1r[p] + k0),
                                       (__attribute__((address_space(3))) void*)&As1[(p * 256 + tid) * 8], 16, 0, 0);
      __builtin_amdgcn_global_load_lds((const __attribute__((address_space(1))) void*)(a3r[p] + k0),
                                       (__attribute__((address_space(3))) void*)&As3[(p * 256 + tid) * 8], 16, 0, 0);
      __builtin_amdgcn_global_load_lds((const __attribute__((address_space(1))) void*)(b1r[p] + k0),
                                       (__attribute__((address_space(3))) void*)&Bs1[(p * 256 + tid) * 8], 16, 0, 0);
      __builtin_amdgcn_global_load_lds((const __attribute__((address_space(1))) void*)(b3r[p] + k0),
                                       (__attribute__((address_space(3))) void*)&Bs3[(p * 256 + tid) * 8], 16, 0, 0);
    }
    __syncthreads();

    short8 av1[4], av3[4], bv1[4], bv3[4];
#pragma unroll
    for (int mi = 0; mi < 4; ++mi) {
      av1[mi] = *(const short8*)&As1[(wm + mi * 16 + (lane & 15)) * 32 + (lane >> 4) * 8];
      av3[mi] = *(const short8*)&As3[(wm + mi * 16 + (lane & 15)) * 32 + (lane >> 4) * 8];
    }
#pragma unroll
    for (int ni = 0; ni < 4; ++ni) {
      bv1[ni] = *(const short8*)&Bs1[(wn + ni * 16 + (lane & 15)) * 32 + (lane >> 4) * 8];
      bv3[ni] = *(const short8*)&Bs3[(wn + ni * 16 + (lane & 15)) * 32 + (lane >> 4) * 8];
    }
#pragma unroll
    for (int mi = 0; mi < 4; ++mi)
#pragma unroll
      for (int ni = 0; ni < 4; ++ni) {
        acc1[mi][ni] = __builtin_amdgcn_mfma_f32_16x16x32_bf16(av1[mi], bv1[ni], acc1[mi][ni], 0, 0, 0);
        acc3[mi][ni] = __builtin_amdgcn_mfma_f32_16x16x32_bf16(av3[mi], bv3[ni], acc3[mi][ni], 0, 0, 0);
      }
  }

  const int er = (lane >> 4) * 4;
  const int ec = lane & 15;
#pragma unroll
  for (int mi = 0; mi < 4; ++mi)
#pragma unroll
    for (int ni = 0; ni < 4; ++ni)
#pragma unroll
      for (int j = 0; j < 4; ++j) {
        int r = row0 + wm + mi * 16 + er + j;
        int c = col0 + wn + ni * 16 + ec;
        if (r < M && c < I_DIM) {
          int t = tok[r];
          float w = wrow[r];
          float g = acc1[mi][ni][j] + b2f(bgate[(long)t * I_DIM + c]);
          float u = acc3[mi][ni][j] + b2f(bup[(long)t * I_DIM + c]);
          float s = g / (1.f + __expf(-g));
          H[(long)r * I_DIM + c] = f2b(w * s * u);
        }
      }
}

// ---------------- launch ----------------
extern "C" void kernel_launch(void* const* d_in, const int* in_sizes, int n_in,
                              void* d_out, int out_size, void* d_ws, size_t ws_size,
                              hipStream_t stream) {
  const float* x   = (const float*)d_in[0];
  const float* gw  = (const float*)d_in[1];
  const float* Wm1 = (const float*)d_in[2];
  const float* Wm2 = (const float*)d_in[3];
  const float* Wm3 = (const float*)d_in[4];
  const float* du1 = (const float*)d_in[5];
  const float* dv1 = (const float*)d_in[6];
  const float* du2 = (const float*)d_in[7];
  const float* dv2 = (const float*)d_in[8];
  const float* du3 = (const float*)d_in[9];
  const float* dv3 = (const float*)d_in[10];

  float* out_final  = (float*)d_out;                    // [T,H] f32
  float* out_logits = out_final + (long)T_TOK * H_DIM;  // [T,E] f32

  char* p = (char*)d_ws;
  auto alloc = [&](size_t bytes) {
    char* r = p;
    p += (bytes + 255) & ~(size_t)255;
    return r;
  };

  // small control buffers
  float* comb   = (float*)alloc((size_t)T_TOK * E_NUM * 4);
  float* wrow   = (float*)alloc((size_t)P_PAIRS * 4);
  int* cnt      = (int*)alloc(64);
  int* cursor   = (int*)alloc(64);
  int* seg      = (int*)alloc(64);
  int* sel_e    = (int*)alloc((size_t)T_TOK * 2 * 4);
  int* tok      = (int*)alloc((size_t)P_PAIRS * 4);
  int* row_of   = (int*)alloc((size_t)T_TOK * 2 * 4);
  // big buffers (with aliasing)
  ushort* bgate_b = (ushort*)alloc((size_t)T_TOK * I_DIM * 2);   // 14.7MB ; reused as hc
  ushort* bup_b   = (ushort*)alloc((size_t)T_TOK * I_DIM * 2);   // 14.7MB ; reused as deltab
  ushort* hmidg   = (ushort*)alloc((size_t)P_PAIRS * I_DIM * 2); // 29.4MB
  ushort* t1g     = (ushort*)alloc((size_t)P_PAIRS * RP * 2);
  ushort* t3g     = (ushort*)alloc((size_t)P_PAIRS * RP * 2);
  ushort* t2g     = (ushort*)alloc((size_t)P_PAIRS * RP * 2);
  ushort* du1b    = (ushort*)alloc((size_t)E_NUM * I_DIM * RP * 2);  // 18.3MB
  ushort* du3b    = (ushort*)alloc((size_t)E_NUM * I_DIM * RP * 2);  // 18.3MB
  ushort* du2b    = (ushort*)alloc((size_t)E_NUM * H_DIM * RP * 2);  // 5.2MB
  ushort* hc      = bgate_b;  // alias: bgate dead after gemm_hmid
  ushort* deltab  = bup_b;    // alias: bup dead after gemm_hmid (8.4MB <= 14.7MB)

  size_t needed = (size_t)(p - (char*)d_ws);
  if (ws_size < needed) return;  // clean diagnostic failure instead of OOB crash

  dim3 blk(256);

  init_kernel<<<1, 64, 0, stream>>>(cnt, cursor);
  router_kernel<<<T_TOK / 4, 256, 0, stream>>>(x, gw, out_logits, comb, sel_e, cnt);
  scan_kernel<<<1, 64, 0, stream>>>(cnt, seg);
  assign_kernel<<<4, 256, 0, stream>>>(sel_e, comb, seg, cursor, tok, wrow, row_of);

  // pad+cast the du matrices (only bf16 staging copies we keep)
  padcast_kernel<<<4096, 256, 0, stream>>>(du1, du1b, (long)E_NUM * I_DIM);
  padcast_kernel<<<4096, 256, 0, stream>>>(du3, du3b, (long)E_NUM * I_DIM);
  padcast_kernel<<<4096, 256, 0, stream>>>(du2, du2b, (long)E_NUM * H_DIM);

  // base_gate / base_up : [1024,7168] bf16 = x @ Wm{1,3}^T
  gemm_f<1, 1, 1, 0, 0><<<dim3(I_DIM / 128, T_TOK / 128, 1), blk, 0, stream>>>(
      x, H_DIM, Wm1, H_DIM, 0L, T_TOK, I_DIM, H_DIM, I_DIM,
      nullptr, bgate_b, I_DIM, nullptr, nullptr, nullptr);
  gemm_f<1, 1, 1, 0, 0><<<dim3(I_DIM / 128, T_TOK / 128, 1), blk, 0, stream>>>(
      x, H_DIM, Wm3, H_DIM, 0L, T_TOK, I_DIM, H_DIM, I_DIM,
      nullptr, bup_b, I_DIM, nullptr, nullptr, nullptr);

  // t1g/t3g : per-expert [cnt_e,160] bf16 = x[tok] @ dv{1,3}[e]^T  (zero pad col 159)
  gemm_f<1, 1, 1, 1, 1><<<dim3(2, 8, E_NUM), blk, 0, stream>>>(
      x, H_DIM, dv1, H_DIM, (long)R_RANK * H_DIM, 0, R_RANK, H_DIM, RP,
      nullptr, t1g, RP, tok, seg, cnt);
  gemm_f<1, 1, 1, 1, 1><<<dim3(2, 8, E_NUM), blk, 0, stream>>>(
      x, H_DIM, dv3, H_DIM, (long)R_RANK * H_DIM, 0, R_RANK, H_DIM, RP,
      nullptr, t3g, RP, tok, seg, cnt);

  // hmid : fused dual expansion + bias + silu*up*weight -> bf16 [2048,7168]
  gemm_hmid<<<dim3(I_DIM / 128, 8, E_NUM), blk, 0, stream>>>(
      t1g, t3g, du1b, du3b, bgate_b, bup_b, tok, wrow, seg, cnt, hmidg);

  // hc[t] = hmid[row0] + hmid[row1]   (writes over bgate region)
  hcomb_kernel<<<(int)(((long)T_TOK * I_DIM / 8 + 255) / 256), 256, 0, stream>>>(hmidg, row_of, hc);

  // down proj: out = hc @ Wm2^T  (f32 out)
  gemm_f<0, 1, 0, 0, 0><<<dim3(H_DIM / 128, T_TOK / 128, 1), blk, 0, stream>>>(
      hc, I_DIM, Wm2, I_DIM, 0L, T_TOK, H_DIM, I_DIM, H_DIM,
      out_final, nullptr, H_DIM, nullptr, nullptr, nullptr);

  // t2g : per-expert [cnt_e,160] bf16 = hmid @ dv2[e]^T  (zero pad col 159)
  gemm_f<0, 1, 1, 1, 0><<<dim3(2, 8, E_NUM), blk, 0, stream>>>(
      hmidg, I_DIM, dv2, I_DIM, (long)R_RANK * I_DIM, 0, R_RANK, I_DIM, RP,
      nullptr, t2g, RP, tok, seg, cnt);

  // deltab : per-expert [cnt_e,2048] bf16 = t2g @ du2[e]^T  (writes over bup region)
  gemm_f<0, 0, 1, 1, 0><<<dim3(H_DIM / 128, 8, E_NUM), blk, 0, stream>>>(
      t2g, RP, du2b, RP, (long)H_DIM * RP, 0, H_DIM, RP, H_DIM,
      nullptr, deltab, H_DIM, tok, seg, cnt);

  // out += delta[row0] + delta[row1]
  finalfix_kernel<<<(int)(((long)T_TOK * H_DIM / 4 + 255) / 256), 256, 0, stream>>>(
      out_final, deltab, row_of);
}

// Round 3
// 564.191 us; speedup vs baseline: 1.8708x; 1.8708x over previous
//
#include <hip/hip_runtime.h>

#define T_TOK 1024
#define H_DIM 2048
#define I_DIM 7168
#define E_NUM 8
#define R_RANK 159
#define RP 160
#define P_PAIRS 2048

typedef __attribute__((ext_vector_type(8))) short short8;
typedef __attribute__((ext_vector_type(4))) float f32x4;

__device__ __forceinline__ ushort f2b(float f) {
  uint u = __float_as_uint(f);
  uint r = (u + 0x7FFFu + ((u >> 16) & 1u)) >> 16;
  return (ushort)r;
}
__device__ __forceinline__ float b2f(ushort u) {
  return __uint_as_float(((uint)u) << 16);
}
__device__ __forceinline__ short8 pack8(float4 a, float4 b) {
  short8 o;
  o[0] = (short)f2b(a.x); o[1] = (short)f2b(a.y); o[2] = (short)f2b(a.z); o[3] = (short)f2b(a.w);
  o[4] = (short)f2b(b.x); o[5] = (short)f2b(b.y); o[6] = (short)f2b(b.z); o[7] = (short)f2b(b.w);
  return o;
}

// ---------------- router ----------------
__global__ __launch_bounds__(256) void router_kernel(
    const float* __restrict__ x, const float* __restrict__ gw,
    float* __restrict__ logits, float* __restrict__ comb,
    int* __restrict__ sel_e, int* __restrict__ cnt) {
  int wave = threadIdx.x >> 6, lane = threadIdx.x & 63;
  int t = blockIdx.x * 4 + wave;
  const float* xr = x + (long)t * H_DIM;
  float acc[8] = {0.f,0.f,0.f,0.f,0.f,0.f,0.f,0.f};
  for (int h = lane * 4; h < H_DIM; h += 256) {
    const float4 xv = *(const float4*)&xr[h];
#pragma unroll
    for (int e = 0; e < 8; ++e) {
      const float4 gv = *(const float4*)&gw[e * H_DIM + h];
      acc[e] += xv.x * gv.x + xv.y * gv.y + xv.z * gv.z + xv.w * gv.w;
    }
  }
#pragma unroll
  for (int off = 32; off > 0; off >>= 1)
#pragma unroll
    for (int e = 0; e < 8; ++e) acc[e] += __shfl_down(acc[e], off);
  if (lane == 0) {
#pragma unroll
    for (int e = 0; e < 8; ++e) logits[(long)t * 8 + e] = acc[e];
    int i0 = 0;
    for (int e = 1; e < 8; ++e) if (acc[e] > acc[i0]) i0 = e;
    int i1 = (i0 == 0) ? 1 : 0;
    for (int e = 0; e < 8; ++e) if (e != i0 && acc[e] > acc[i1]) i1 = e;
    float ee = __expf(acc[i1] - acc[i0]);
    float w0 = 1.f / (1.f + ee), w1 = ee / (1.f + ee);
    for (int e = 0; e < 8; ++e) comb[t * 8 + e] = 0.f;
    comb[t * 8 + i0] = w0;
    comb[t * 8 + i1] = w1;
    sel_e[t * 2] = i0;
    sel_e[t * 2 + 1] = i1;
    atomicAdd(&cnt[i0], 1);
    atomicAdd(&cnt[i1], 1);
  }
}

__global__ void init_kernel(int* cnt, int* cursor) {
  int i = threadIdx.x;
  if (i < 8) { cnt[i] = 0; cursor[i] = 0; }
}

__global__ void scan_kernel(const int* cnt, int* seg) {
  if (threadIdx.x == 0) {
    int s = 0;
    for (int e = 0; e < 8; ++e) { seg[e] = s; s += cnt[e]; }
    seg[8] = s;
  }
}

__global__ void assign_kernel(const int* __restrict__ sel_e, const float* __restrict__ comb,
                              const int* __restrict__ seg, int* __restrict__ cursor,
                              int* __restrict__ tok, float* __restrict__ wrow,
                              int* __restrict__ row_of) {
  int t = blockIdx.x * blockDim.x + threadIdx.x;
  if (t >= T_TOK) return;
  for (int k = 0; k < 2; ++k) {
    int e = sel_e[t * 2 + k];
    int pos = atomicAdd(&cursor[e], 1);
    int row = seg[e] + pos;
    tok[row] = t;
    wrow[row] = comb[t * 8 + e];
    row_of[t * 2 + k] = row;
  }
}

// ---------------- casts ----------------
// flat f32 -> bf16, 8 elems/thread
__global__ void cast8_kernel(const float* __restrict__ src, ushort* __restrict__ dst, long n8) {
  long idx = (long)blockIdx.x * blockDim.x + threadIdx.x;
  long stride = (long)gridDim.x * blockDim.x;
  for (long i = idx; i < n8; i += stride) {
    const float4 a = *(const float4*)&src[i * 8];
    const float4 b = *(const float4*)&src[i * 8 + 4];
    *(short8*)&dst[i * 8] = pack8(a, b);
  }
}

// [rows,159] f32 -> [rows,160] bf16, 8 dst elems/thread
__global__ void padcast8_kernel(const float* __restrict__ src, ushort* __restrict__ dst, long rows) {
  long n8 = rows * (RP / 8);
  long idx = (long)blockIdx.x * blockDim.x + threadIdx.x;
  long stride = (long)gridDim.x * blockDim.x;
  for (long i = idx; i < n8; i += stride) {
    long row = i / (RP / 8);
    int c0 = (int)(i % (RP / 8)) * 8;
    short8 o;
#pragma unroll
    for (int j = 0; j < 8; ++j) {
      int c = c0 + j;
      o[j] = (c < R_RANK) ? (short)f2b(src[row * R_RANK + c]) : (short)0;
    }
    *(short8*)&dst[row * RP + c0] = o;
  }
}

// hc[t,i] = hmid[row0,i] + hmid[row1,i]   (bf16)
__global__ void hcomb_kernel(const ushort* __restrict__ hmid, const int* __restrict__ row_of,
                             ushort* __restrict__ hc) {
  long idx = (long)blockIdx.x * blockDim.x + threadIdx.x;
  long total = (long)T_TOK * I_DIM / 8;
  if (idx >= total) return;
  long i = idx * 8;
  int t = (int)(i / I_DIM);
  int col = (int)(i % I_DIM);
  int r0 = row_of[t * 2], r1 = row_of[t * 2 + 1];
  const short8 a = *(const short8*)&hmid[(long)r0 * I_DIM + col];
  const short8 b = *(const short8*)&hmid[(long)r1 * I_DIM + col];
  short8 o;
#pragma unroll
  for (int j = 0; j < 8; ++j)
    o[j] = (short)f2b(b2f((ushort)a[j]) + b2f((ushort)b[j]));
  *(short8*)&hc[i] = o;
}

// plan B: out[t,h] += delta[row0,h] + delta[row1,h]  (delta bf16)
__global__ void finalfix_kernel(float* __restrict__ out, const ushort* __restrict__ delta,
                                const int* __restrict__ row_of) {
  long idx = (long)blockIdx.x * blockDim.x + threadIdx.x;
  long total = (long)T_TOK * H_DIM / 4;
  if (idx >= total) return;
  long i = idx * 4;
  int t = (int)(i / H_DIM);
  int col = (int)(i % H_DIM);
  int r0 = row_of[t * 2], r1 = row_of[t * 2 + 1];
  float4 d = *(float4*)&out[i];
  d.x += b2f(delta[(long)r0 * H_DIM + col + 0]) + b2f(delta[(long)r1 * H_DIM + col + 0]);
  d.y += b2f(delta[(long)r0 * H_DIM + col + 1]) + b2f(delta[(long)r1 * H_DIM + col + 1]);
  d.z += b2f(delta[(long)r0 * H_DIM + col + 2]) + b2f(delta[(long)r1 * H_DIM + col + 2]);
  d.w += b2f(delta[(long)r0 * H_DIM + col + 3]) + b2f(delta[(long)r1 * H_DIM + col + 3]);
  *(float4*)&out[i] = d;
}

// plan A: out[t,h] = sum_{ks<4} dp[ks][t][h] + delta[row0,h] + delta[row1,h]
__global__ void finalfixA_kernel(float* __restrict__ out, const float* __restrict__ dp,
                                 const ushort* __restrict__ delta, const int* __restrict__ row_of) {
  long idx = (long)blockIdx.x * blockDim.x + threadIdx.x;
  long total = (long)T_TOK * H_DIM / 4;
  if (idx >= total) return;
  long i = idx * 4;
  int t = (int)(i / H_DIM);
  int col = (int)(i % H_DIM);
  int r0 = row_of[t * 2], r1 = row_of[t * 2 + 1];
  const long plane = (long)T_TOK * H_DIM;
  float4 s = *(const float4*)&dp[i];
#pragma unroll
  for (int k = 1; k < 4; ++k) {
    const float4 q = *(const float4*)&dp[k * plane + i];
    s.x += q.x; s.y += q.y; s.z += q.z; s.w += q.w;
  }
  s.x += b2f(delta[(long)r0 * H_DIM + col + 0]) + b2f(delta[(long)r1 * H_DIM + col + 0]);
  s.y += b2f(delta[(long)r0 * H_DIM + col + 1]) + b2f(delta[(long)r1 * H_DIM + col + 1]);
  s.z += b2f(delta[(long)r0 * H_DIM + col + 2]) + b2f(delta[(long)r1 * H_DIM + col + 2]);
  s.w += b2f(delta[(long)r0 * H_DIM + col + 3]) + b2f(delta[(long)r1 * H_DIM + col + 3]);
  *(float4*)&out[i] = s;
}

// sum KS f32 planes -> bf16
template <int KS>
__global__ void reduce_cast_kernel(const float* __restrict__ P, long plane,
                                   ushort* __restrict__ out, long n) {
  long i = (long)blockIdx.x * blockDim.x + threadIdx.x;
  if (i >= n) return;
  float s = 0.f;
#pragma unroll
  for (int k = 0; k < KS; ++k) s += P[(long)k * plane + i];
  out[i] = f2b(s);
}

// ---------------- general GEMM: C[M,N] = A[M,K] @ B[N,K]^T ----------------
template <int AF32, int BF32, int CBF16, int PEREXP, int AMAP>
__global__ __launch_bounds__(256) void gemm_f(
    const void* __restrict__ Ap, int lda,
    const void* __restrict__ Bp, int ldb, long Bstride,
    int M, int N, int K, int Npad,
    float* __restrict__ Cf, ushort* __restrict__ Cb, int ldc,
    const int* __restrict__ tok, const int* __restrict__ seg, const int* __restrict__ cnt) {
  __shared__ ushort As[128 * 32];
  __shared__ ushort Bs[128 * 32];
  const float* Af = (const float*)Ap;
  const ushort* Ab = (const ushort*)Ap;
  const float* Bf = (const float*)Bp;
  const ushort* Bb = (const ushort*)Bp;
  const int* amap = tok;
  if (PEREXP) {
    int e = blockIdx.z;
    int m0 = seg[e];
    M = cnt[e];
    if ((int)(blockIdx.y * 128) >= M) return;
    if (AMAP) {
      amap = tok + m0;
    } else {
      if (AF32) Af += (long)m0 * lda; else Ab += (long)m0 * lda;
    }
    if (BF32) Bf += (long)e * Bstride; else Bb += (long)e * Bstride;
    if (CBF16) Cb += (long)m0 * ldc; else Cf += (long)m0 * ldc;
  }
  const int tid = threadIdx.x;
  const int lane = tid & 63, wave = tid >> 6;
  const int wm = (wave >> 1) * 64, wn = (wave & 1) * 64;
  const int row0 = blockIdx.y * 128, col0 = blockIdx.x * 128;
  const int sub_r = tid >> 2;
  const int sub_c = (tid & 3) * 8;

  const float* afrow[2]; const ushort* abrow[2];
  const float* bfrow[2]; const ushort* bbrow[2];
#pragma unroll
  for (int p = 0; p < 2; ++p) {
    int r = row0 + p * 64 + sub_r; if (r > M - 1) r = M - 1;
    if (AMAP) r = amap[r];
    if (AF32) afrow[p] = Af + (long)r * lda + sub_c;
    else      abrow[p] = Ab + (long)r * lda + sub_c;
    int q = col0 + p * 64 + sub_r; if (q > N - 1) q = N - 1;
    if (BF32) bfrow[p] = Bf + (long)q * ldb + sub_c;
    else      bbrow[p] = Bb + (long)q * ldb + sub_c;
  }

  f32x4 acc[4][4] = {};

  for (int k0 = 0; k0 < K; k0 += 32) {
    float4 a0[2], a1[2], b0[2], b1[2];
    if (AF32) {
#pragma unroll
      for (int p = 0; p < 2; ++p) {
        a0[p] = *(const float4*)(afrow[p] + k0);
        a1[p] = *(const float4*)(afrow[p] + k0 + 4);
      }
    }
    if (BF32) {
#pragma unroll
      for (int p = 0; p < 2; ++p) {
        b0[p] = *(const float4*)(bfrow[p] + k0);
        b1[p] = *(const float4*)(bfrow[p] + k0 + 4);
      }
    }
    __syncthreads();
#pragma unroll
    for (int p = 0; p < 2; ++p) {
      if (AF32) {
        *(short8*)&As[(p * 256 + tid) * 8] = pack8(a0[p], a1[p]);
      } else {
        __builtin_amdgcn_global_load_lds((const __attribute__((address_space(1))) void*)(abrow[p] + k0),
                                         (__attribute__((address_space(3))) void*)&As[(p * 256 + tid) * 8],
                                         16, 0, 0);
      }
      if (BF32) {
        *(short8*)&Bs[(p * 256 + tid) * 8] = pack8(b0[p], b1[p]);
      } else {
        __builtin_amdgcn_global_load_lds((const __attribute__((address_space(1))) void*)(bbrow[p] + k0),
                                         (__attribute__((address_space(3))) void*)&Bs[(p * 256 + tid) * 8],
                                         16, 0, 0);
      }
    }
    __syncthreads();

    short8 av[4], bv[4];
#pragma unroll
    for (int mi = 0; mi < 4; ++mi)
      av[mi] = *(const short8*)&As[(wm + mi * 16 + (lane & 15)) * 32 + (lane >> 4) * 8];
#pragma unroll
    for (int ni = 0; ni < 4; ++ni)
      bv[ni] = *(const short8*)&Bs[(wn + ni * 16 + (lane & 15)) * 32 + (lane >> 4) * 8];
#pragma unroll
    for (int mi = 0; mi < 4; ++mi)
#pragma unroll
      for (int ni = 0; ni < 4; ++ni)
        acc[mi][ni] = __builtin_amdgcn_mfma_f32_16x16x32_bf16(av[mi], bv[ni], acc[mi][ni], 0, 0, 0);
  }

  const int er = (lane >> 4) * 4;
  const int ec = lane & 15;
#pragma unroll
  for (int mi = 0; mi < 4; ++mi)
#pragma unroll
    for (int ni = 0; ni < 4; ++ni)
#pragma unroll
      for (int j = 0; j < 4; ++j) {
        int r = row0 + wm + mi * 16 + er + j;
        int c = col0 + wn + ni * 16 + ec;
        if (r < M && c < Npad) {
          float v = (c < N) ? acc[mi][ni][j] : 0.f;
          if (CBF16) Cb[(long)r * ldc + c] = f2b(v);
          else       Cf[(long)r * ldc + c] = v;
        }
      }
}

// ---------------- split-K GEMM (bf16 in, f32 partials) ----------------
// P[ks][m, c] = A[m, kbase:kbase+kchunk] @ B[c, ...]^T ; cols [N,Npad) get 0.
template <int PEREXP, int KS>
__global__ __launch_bounds__(256) void gemm_splitk(
    const ushort* __restrict__ A, int lda,
    const ushort* __restrict__ B, int ldb, long Bstride,
    int M, int N, int Npad, int kchunk,
    float* __restrict__ P, int ldc, long Pplane,
    const int* __restrict__ seg, const int* __restrict__ cnt) {
  __shared__ ushort As[128 * 32];
  __shared__ ushort Bs[128 * 32];
  int ks;
  if (PEREXP) {
    int e = blockIdx.z / KS;
    ks = blockIdx.z % KS;
    int m0 = seg[e];
    M = cnt[e];
    if ((int)(blockIdx.y * 128) >= M) return;
    A += (long)m0 * lda;
    B += (long)e * Bstride;
    P += (long)m0 * ldc;
  } else {
    ks = blockIdx.z;
  }
  P += (long)ks * Pplane;
  const int kbase = ks * kchunk;

  const int tid = threadIdx.x;
  const int lane = tid & 63, wave = tid >> 6;
  const int wm = (wave >> 1) * 64, wn = (wave & 1) * 64;
  const int row0 = blockIdx.y * 128, col0 = blockIdx.x * 128;
  const int sub_r = tid >> 2;
  const int sub_c = (tid & 3) * 8;

  const ushort *ar[2], *br[2];
#pragma unroll
  for (int p = 0; p < 2; ++p) {
    int r = row0 + p * 64 + sub_r; if (r > M - 1) r = M - 1;
    ar[p] = A + (long)r * lda + kbase + sub_c;
    int q = col0 + p * 64 + sub_r; if (q > N - 1) q = N - 1;
    br[p] = B + (long)q * ldb + kbase + sub_c;
  }

  f32x4 acc[4][4] = {};

  for (int kk = 0; kk < kchunk; kk += 32) {
    __syncthreads();
#pragma unroll
    for (int p = 0; p < 2; ++p) {
      __builtin_amdgcn_global_load_lds((const __attribute__((address_space(1))) void*)(ar[p] + kk),
                                       (__attribute__((address_space(3))) void*)&As[(p * 256 + tid) * 8], 16, 0, 0);
      __builtin_amdgcn_global_load_lds((const __attribute__((address_space(1))) void*)(br[p] + kk),
                                       (__attribute__((address_space(3))) void*)&Bs[(p * 256 + tid) * 8], 16, 0, 0);
    }
    __syncthreads();

    short8 av[4], bv[4];
#pragma unroll
    for (int mi = 0; mi < 4; ++mi)
      av[mi] = *(const short8*)&As[(wm + mi * 16 + (lane & 15)) * 32 + (lane >> 4) * 8];
#pragma unroll
    for (int ni = 0; ni < 4; ++ni)
      bv[ni] = *(const short8*)&Bs[(wn + ni * 16 + (lane & 15)) * 32 + (lane >> 4) * 8];
#pragma unroll
    for (int mi = 0; mi < 4; ++mi)
#pragma unroll
      for (int ni = 0; ni < 4; ++ni)
        acc[mi][ni] = __builtin_amdgcn_mfma_f32_16x16x32_bf16(av[mi], bv[ni], acc[mi][ni], 0, 0, 0);
  }

  const int er = (lane >> 4) * 4;
  const int ec = lane & 15;
#pragma unroll
  for (int mi = 0; mi < 4; ++mi)
#pragma unroll
    for (int ni = 0; ni < 4; ++ni)
#pragma unroll
      for (int j = 0; j < 4; ++j) {
        int r = row0 + wm + mi * 16 + er + j;
        int c = col0 + wn + ni * 16 + ec;
        if (r < M && c < Npad)
          P[(long)r * ldc + c] = (c < N) ? acc[mi][ni][j] : 0.f;
      }
}

// ---------------- fused dual-B split-K8 GEMM for t1/t3 ----------------
// A = xb[tok[...]] (gathered), B1/B3 = dv1b/dv3b[e]; K chunk = 256 (8 iters).
__global__ __launch_bounds__(256) void gemm_t13(
    const ushort* __restrict__ xb, const ushort* __restrict__ dv1b,
    const ushort* __restrict__ dv3b, const int* __restrict__ tok,
    const int* __restrict__ seg, const int* __restrict__ cnt,
    float* __restrict__ p1, float* __restrict__ p3) {
  __shared__ ushort As[128 * 32], Bs1[128 * 32], Bs3[128 * 32];
  const int e = blockIdx.z >> 3;
  const int ks = blockIdx.z & 7;
  const int m0 = seg[e], M = cnt[e];
  const int row0 = blockIdx.y * 128, col0 = blockIdx.x * 128;
  if (row0 >= M) return;
  const int kbase = ks * 256;

  const int tid = threadIdx.x;
  const int lane = tid & 63, wave = tid >> 6;
  const int wm = (wave >> 1) * 64, wn = (wave & 1) * 64;
  const int sub_r = tid >> 2;
  const int sub_c = (tid & 3) * 8;

  const ushort *ar[2], *b1r[2], *b3r[2];
#pragma unroll
  for (int p = 0; p < 2; ++p) {
    int r = row0 + p * 64 + sub_r; if (r > M - 1) r = M - 1;
    int t = tok[m0 + r];
    ar[p] = xb + (long)t * H_DIM + kbase + sub_c;
    int q = col0 + p * 64 + sub_r; if (q > R_RANK - 1) q = R_RANK - 1;
    b1r[p] = dv1b + (long)e * R_RANK * H_DIM + (long)q * H_DIM + kbase + sub_c;
    b3r[p] = dv3b + (long)e * R_RANK * H_DIM + (long)q * H_DIM + kbase + sub_c;
  }

  f32x4 acc1[4][4] = {}, acc3[4][4] = {};

  for (int kk = 0; kk < 256; kk += 32) {
    __syncthreads();
#pragma unroll
    for (int p = 0; p < 2; ++p) {
      __builtin_amdgcn_global_load_lds((const __attribute__((address_space(1))) void*)(ar[p] + kk),
                                       (__attribute__((address_space(3))) void*)&As[(p * 256 + tid) * 8], 16, 0, 0);
      __builtin_amdgcn_global_load_lds((const __attribute__((address_space(1))) void*)(b1r[p] + kk),
                                       (__attribute__((address_space(3))) void*)&Bs1[(p * 256 + tid) * 8], 16, 0, 0);
      __builtin_amdgcn_global_load_lds((const __attribute__((address_space(1))) void*)(b3r[p] + kk),
                                       (__attribute__((address_space(3))) void*)&Bs3[(p * 256 + tid) * 8], 16, 0, 0);
    }
    __syncthreads();

    short8 av[4], bv1[4], bv3[4];
#pragma unroll
    for (int mi = 0; mi < 4; ++mi)
      av[mi] = *(const short8*)&As[(wm + mi * 16 + (lane & 15)) * 32 + (lane >> 4) * 8];
#pragma unroll
    for (int ni = 0; ni < 4; ++ni) {
      bv1[ni] = *(const short8*)&Bs1[(wn + ni * 16 + (lane & 15)) * 32 + (lane >> 4) * 8];
      bv3[ni] = *(const short8*)&Bs3[(wn + ni * 16 + (lane & 15)) * 32 + (lane >> 4) * 8];
    }
#pragma unroll
    for (int mi = 0; mi < 4; ++mi)
#pragma unroll
      for (int ni = 0; ni < 4; ++ni) {
        acc1[mi][ni] = __builtin_amdgcn_mfma_f32_16x16x32_bf16(av[mi], bv1[ni], acc1[mi][ni], 0, 0, 0);
        acc3[mi][ni] = __builtin_amdgcn_mfma_f32_16x16x32_bf16(av[mi], bv3[ni], acc3[mi][ni], 0, 0, 0);
      }
  }

  const int er = (lane >> 4) * 4;
  const int ec = lane & 15;
  const long plane = (long)P_PAIRS * RP;
#pragma unroll
  for (int mi = 0; mi < 4; ++mi)
#pragma unroll
    for (int ni = 0; ni < 4; ++ni)
#pragma unroll
      for (int j = 0; j < 4; ++j) {
        int r = row0 + wm + mi * 16 + er + j;
        int c = col0 + wn + ni * 16 + ec;
        if (r < M && c < RP) {
          long o = (long)ks * plane + (long)(m0 + r) * RP + c;
          p1[o] = (c < R_RANK) ? acc1[mi][ni][j] : 0.f;
          p3[o] = (c < R_RANK) ? acc3[mi][ni][j] : 0.f;
        }
      }
}

// ---------------- fused dual GEMM: gate/up expansion + silu + weight ----------------
__global__ __launch_bounds__(256) void gemm_hmid(
    const ushort* __restrict__ t1g, const ushort* __restrict__ t3g,
    const ushort* __restrict__ du1b, const ushort* __restrict__ du3b,
    const ushort* __restrict__ bgate, const ushort* __restrict__ bup,
    const int* __restrict__ tok, const float* __restrict__ wrow,
    const int* __restrict__ seg, const int* __restrict__ cnt,
    ushort* __restrict__ hmid) {
  __shared__ ushort As1[128 * 32], As3[128 * 32];
  __shared__ ushort Bs1[128 * 32], Bs3[128 * 32];
  int e = blockIdx.z;
  int m0 = seg[e], M = cnt[e];
  if ((int)(blockIdx.y * 128) >= M) return;
  const ushort* A1 = t1g + (long)m0 * RP;
  const ushort* A3 = t3g + (long)m0 * RP;
  const ushort* B1 = du1b + (long)e * I_DIM * RP;
  const ushort* B3 = du3b + (long)e * I_DIM * RP;
  tok += m0; wrow += m0;
  ushort* H = hmid + (long)m0 * I_DIM;

  const int tid = threadIdx.x;
  const int lane = tid & 63, wave = tid >> 6;
  const int wm = (wave >> 1) * 64, wn = (wave & 1) * 64;
  const int row0 = blockIdx.y * 128, col0 = blockIdx.x * 128;
  const int sub_r = tid >> 2;
  const int sub_c = (tid & 3) * 8;

  const ushort *a1r[2], *a3r[2], *b1r[2], *b3r[2];
#pragma unroll
  for (int p = 0; p < 2; ++p) {
    int r = row0 + p * 64 + sub_r; if (r > M - 1) r = M - 1;
    a1r[p] = A1 + (long)r * RP + sub_c;
    a3r[p] = A3 + (long)r * RP + sub_c;
    int q = col0 + p * 64 + sub_r; if (q > I_DIM - 1) q = I_DIM - 1;
    b1r[p] = B1 + (long)q * RP + sub_c;
    b3r[p] = B3 + (long)q * RP + sub_c;
  }

  f32x4 acc1[4][4] = {}, acc3[4][4] = {};

  for (int k0 = 0; k0 < RP; k0 += 32) {
    __syncthreads();
#pragma unroll
    for (int p = 0; p < 2; ++p) {
      __builtin_amdgcn_global_load_lds((const __attribute__((address_space(1))) void*)(a1r[p] + k0),
                                       (__attribute__((address_space(3))) void*)&As1[(p * 256 + tid) * 8], 16, 0, 0);
      __builtin_amdgcn_global_load_lds((const __attribute__((address_space(1))) void*)(a3r[p] + k0),
                                       (__attribute__((address_space(3))) void*)&As3[(p * 256 + tid) * 8], 16, 0, 0);
      __builtin_amdgcn_global_load_lds((const __attribute__((address_space(1))) void*)(b1r[p] + k0),
                                       (__attribute__((address_space(3))) void*)&Bs1[(p * 256 + tid) * 8], 16, 0, 0);
      __builtin_amdgcn_global_load_lds((const __attribute__((address_space(1))) void*)(b3r[p] + k0),
                                       (__attribute__((address_space(3))) void*)&Bs3[(p * 256 + tid) * 8], 16, 0, 0);
    }
    __syncthreads();

    short8 av1[4], av3[4], bv1[4], bv3[4];
#pragma unroll
    for (int mi = 0; mi < 4; ++mi) {
      av1[mi] = *(const short8*)&As1[(wm + mi * 16 + (lane & 15)) * 32 + (lane >> 4) * 8];
      av3[mi] = *(const short8*)&As3[(wm + mi * 16 + (lane & 15)) * 32 + (lane >> 4) * 8];
    }
#pragma unroll
    for (int ni = 0; ni < 4; ++ni) {
      bv1[ni] = *(const short8*)&Bs1[(wn + ni * 16 + (lane & 15)) * 32 + (lane >> 4) * 8];
      bv3[ni] = *(const short8*)&Bs3[(wn + ni * 16 + (lane & 15)) * 32 + (lane >> 4) * 8];
    }
#pragma unroll
    for (int mi = 0; mi < 4; ++mi)
#pragma unroll
      for (int ni = 0; ni < 4; ++ni) {
        acc1[mi][ni] = __builtin_amdgcn_mfma_f32_16x16x32_bf16(av1[mi], bv1[ni], acc1[mi][ni], 0, 0, 0);
        acc3[mi][ni] = __builtin_amdgcn_mfma_f32_16x16x32_bf16(av3[mi], bv3[ni], acc3[mi][ni], 0, 0, 0);
      }
  }

  const int er = (lane >> 4) * 4;
  const int ec = lane & 15;
#pragma unroll
  for (int mi = 0; mi < 4; ++mi)
#pragma unroll
    for (int ni = 0; ni < 4; ++ni)
#pragma unroll
      for (int j = 0; j < 4; ++j) {
        int r = row0 + wm + mi * 16 + er + j;
        int c = col0 + wn + ni * 16 + ec;
        if (r < M && c < I_DIM) {
          int t = tok[r];
          float w = wrow[r];
          float g = acc1[mi][ni][j] + b2f(bgate[(long)t * I_DIM + c]);
          float u = acc3[mi][ni][j] + b2f(bup[(long)t * I_DIM + c]);
          float s = g / (1.f + __expf(-g));
          H[(long)r * I_DIM + c] = f2b(w * s * u);
        }
      }
}

// ---------------- launch ----------------
extern "C" void kernel_launch(void* const* d_in, const int* in_sizes, int n_in,
                              void* d_out, int out_size, void* d_ws, size_t ws_size,
                              hipStream_t stream) {
  const float* x   = (const float*)d_in[0];
  const float* gw  = (const float*)d_in[1];
  const float* Wm1 = (const float*)d_in[2];
  const float* Wm2 = (const float*)d_in[3];
  const float* Wm3 = (const float*)d_in[4];
  const float* du1 = (const float*)d_in[5];
  const float* dv1 = (const float*)d_in[6];
  const float* du2 = (const float*)d_in[7];
  const float* dv2 = (const float*)d_in[8];
  const float* du3 = (const float*)d_in[9];
  const float* dv3 = (const float*)d_in[10];

  float* out_final  = (float*)d_out;
  float* out_logits = out_final + (long)T_TOK * H_DIM;

  char* p = (char*)d_ws;
  auto alloc = [&](size_t bytes) {
    char* r = p;
    p += (bytes + 255) & ~(size_t)255;
    return r;
  };

  // ---- common control buffers ----
  float* comb   = (float*)alloc((size_t)T_TOK * E_NUM * 4);
  float* wrow   = (float*)alloc((size_t)P_PAIRS * 4);
  int* cnt      = (int*)alloc(64);
  int* cursor   = (int*)alloc(64);
  int* seg      = (int*)alloc(64);
  int* sel_e    = (int*)alloc((size_t)T_TOK * 2 * 4);
  int* tok      = (int*)alloc((size_t)P_PAIRS * 4);
  int* row_of   = (int*)alloc((size_t)T_TOK * 2 * 4);
  // ---- big buffers shared by both plans ----
  ushort* bgate_b = (ushort*)alloc((size_t)T_TOK * I_DIM * 2);   // later: hc, then t2 partials
  ushort* bup_b   = (ushort*)alloc((size_t)T_TOK * I_DIM * 2);   // later: deltab
  ushort* hmidg   = (ushort*)alloc((size_t)P_PAIRS * I_DIM * 2); // earlier: t13 partials
  ushort* t1g     = (ushort*)alloc((size_t)P_PAIRS * RP * 2);
  ushort* t3g     = (ushort*)alloc((size_t)P_PAIRS * RP * 2);
  ushort* t2g     = (ushort*)alloc((size_t)P_PAIRS * RP * 2);
  ushort* du1b    = (ushort*)alloc((size_t)E_NUM * I_DIM * RP * 2);  // later: down partials (w/ du3b)
  ushort* du3b    = (ushort*)alloc((size_t)E_NUM * I_DIM * RP * 2);
  ushort* du2b    = (ushort*)alloc((size_t)E_NUM * H_DIM * RP * 2);
  size_t needed_B = (size_t)(p - (char*)d_ws);
  // ---- plan-A extra buffers ----
  ushort* xb   = (ushort*)alloc((size_t)T_TOK * H_DIM * 2);
  ushort* w1b  = (ushort*)alloc((size_t)I_DIM * H_DIM * 2);          // later: w2b
  ushort* w3b  = (ushort*)alloc((size_t)I_DIM * H_DIM * 2);          // later: dv2b
  ushort* dv1b = (ushort*)alloc((size_t)E_NUM * R_RANK * H_DIM * 2);
  ushort* dv3b = (ushort*)alloc((size_t)E_NUM * R_RANK * H_DIM * 2);
  size_t needed_A = (size_t)(p - (char*)d_ws);

  ushort* hc     = bgate_b;
  ushort* deltab = bup_b;

  if (ws_size < needed_B) return;
  const bool planA = (ws_size >= needed_A);

  dim3 blk(256);

  init_kernel<<<1, 64, 0, stream>>>(cnt, cursor);
  router_kernel<<<T_TOK / 4, 256, 0, stream>>>(x, gw, out_logits, comb, sel_e, cnt);
  scan_kernel<<<1, 64, 0, stream>>>(cnt, seg);
  assign_kernel<<<4, 256, 0, stream>>>(sel_e, comb, seg, cursor, tok, wrow, row_of);

  padcast8_kernel<<<4480, 256, 0, stream>>>(du1, du1b, (long)E_NUM * I_DIM);
  padcast8_kernel<<<4480, 256, 0, stream>>>(du3, du3b, (long)E_NUM * I_DIM);
  padcast8_kernel<<<1280, 256, 0, stream>>>(du2, du2b, (long)E_NUM * H_DIM);

  if (planA) {
    // ---- bf16 casts ----
    cast8_kernel<<<1024, 256, 0, stream>>>(x, xb, (long)T_TOK * H_DIM / 8);
    cast8_kernel<<<7168, 256, 0, stream>>>(Wm1, w1b, (long)I_DIM * H_DIM / 8);
    cast8_kernel<<<7168, 256, 0, stream>>>(Wm3, w3b, (long)I_DIM * H_DIM / 8);
    cast8_kernel<<<1272, 256, 0, stream>>>(dv1, dv1b, (long)E_NUM * R_RANK * H_DIM / 8);
    cast8_kernel<<<1272, 256, 0, stream>>>(dv3, dv3b, (long)E_NUM * R_RANK * H_DIM / 8);

    // ---- base_gate / base_up (bf16 global_load_lds path) ----
    gemm_f<0, 0, 1, 0, 0><<<dim3(I_DIM / 128, T_TOK / 128, 1), blk, 0, stream>>>(
        xb, H_DIM, w1b, H_DIM, 0L, T_TOK, I_DIM, H_DIM, I_DIM,
        nullptr, bgate_b, I_DIM, nullptr, nullptr, nullptr);
    gemm_f<0, 0, 1, 0, 0><<<dim3(I_DIM / 128, T_TOK / 128, 1), blk, 0, stream>>>(
        xb, H_DIM, w3b, H_DIM, 0L, T_TOK, I_DIM, H_DIM, I_DIM,
        nullptr, bup_b, I_DIM, nullptr, nullptr, nullptr);

    // w1b/w3b now dead -> cast Wm2 / dv2 into their regions
    ushort* w2b  = w1b;
    ushort* dv2b = w3b;
    cast8_kernel<<<7168, 256, 0, stream>>>(Wm2, w2b, (long)I_DIM * H_DIM / 8);
    cast8_kernel<<<4452, 256, 0, stream>>>(dv2, dv2b, (long)E_NUM * R_RANK * I_DIM / 8);

    // ---- t1/t3 fused dual-B split-K8 (partials in hmidg region) ----
    float* p1 = (float*)hmidg;
    float* p3 = p1 + (long)8 * P_PAIRS * RP;
    gemm_t13<<<dim3(2, 8, 64), blk, 0, stream>>>(xb, dv1b, dv3b, tok, seg, cnt, p1, p3);
    reduce_cast_kernel<8><<<1280, 256, 0, stream>>>(p1, (long)P_PAIRS * RP, t1g, (long)P_PAIRS * RP);
    reduce_cast_kernel<8><<<1280, 256, 0, stream>>>(p3, (long)P_PAIRS * RP, t3g, (long)P_PAIRS * RP);

    // ---- hmid (overwrites the t13 partial region) ----
    gemm_hmid<<<dim3(I_DIM / 128, 8, E_NUM), blk, 0, stream>>>(
        t1g, t3g, du1b, du3b, bgate_b, bup_b, tok, wrow, seg, cnt, hmidg);

    // ---- hc = weighted combine (bgate region) ----
    hcomb_kernel<<<(int)(((long)T_TOK * I_DIM / 8 + 255) / 256), 256, 0, stream>>>(hmidg, row_of, hc);

    // ---- down proj split-K4 (partials in du1b/du3b region) ----
    float* dp = (float*)du1b;
    gemm_splitk<0, 4><<<dim3(H_DIM / 128, T_TOK / 128, 4), blk, 0, stream>>>(
        hc, I_DIM, w2b, I_DIM, 0L, T_TOK, H_DIM, H_DIM, I_DIM / 4,
        dp, H_DIM, (long)T_TOK * H_DIM, nullptr, nullptr);

    // ---- t2 split-K8 (partials in bgate/hc region, dead after down) ----
    float* p2 = (float*)bgate_b;
    gemm_splitk<1, 8><<<dim3(2, 8, 64), blk, 0, stream>>>(
        hmidg, I_DIM, dv2b, I_DIM, (long)R_RANK * I_DIM, 0, R_RANK, RP, I_DIM / 8,
        p2, RP, (long)P_PAIRS * RP, seg, cnt);
    reduce_cast_kernel<8><<<1280, 256, 0, stream>>>(p2, (long)P_PAIRS * RP, t2g, (long)P_PAIRS * RP);

    // ---- delta = t2g @ du2^T (bf16, K=160) ----
    gemm_f<0, 0, 1, 1, 0><<<dim3(H_DIM / 128, 8, E_NUM), blk, 0, stream>>>(
        t2g, RP, du2b, RP, (long)H_DIM * RP, 0, H_DIM, RP, H_DIM,
        nullptr, deltab, H_DIM, tok, seg, cnt);

    // ---- final: out = sum(dp) + delta[row0] + delta[row1] ----
    finalfixA_kernel<<<2048, 256, 0, stream>>>(out_final, dp, deltab, row_of);
  } else {
    // ---------------- plan B: round-2 fallback ----------------
    gemm_f<1, 1, 1, 0, 0><<<dim3(I_DIM / 128, T_TOK / 128, 1), blk, 0, stream>>>(
        x, H_DIM, Wm1, H_DIM, 0L, T_TOK, I_DIM, H_DIM, I_DIM,
        nullptr, bgate_b, I_DIM, nullptr, nullptr, nullptr);
    gemm_f<1, 1, 1, 0, 0><<<dim3(I_DIM / 128, T_TOK / 128, 1), blk, 0, stream>>>(
        x, H_DIM, Wm3, H_DIM, 0L, T_TOK, I_DIM, H_DIM, I_DIM,
        nullptr, bup_b, I_DIM, nullptr, nullptr, nullptr);
    gemm_f<1, 1, 1, 1, 1><<<dim3(2, 8, E_NUM), blk, 0, stream>>>(
        x, H_DIM, dv1, H_DIM, (long)R_RANK * H_DIM, 0, R_RANK, H_DIM, RP,
        nullptr, t1g, RP, tok, seg, cnt);
    gemm_f<1, 1, 1, 1, 1><<<dim3(2, 8, E_NUM), blk, 0, stream>>>(
        x, H_DIM, dv3, H_DIM, (long)R_RANK * H_DIM, 0, R_RANK, H_DIM, RP,
        nullptr, t3g, RP, tok, seg, cnt);
    gemm_hmid<<<dim3(I_DIM / 128, 8, E_NUM), blk, 0, stream>>>(
        t1g, t3g, du1b, du3b, bgate_b, bup_b, tok, wrow, seg, cnt, hmidg);
    hcomb_kernel<<<(int)(((long)T_TOK * I_DIM / 8 + 255) / 256), 256, 0, stream>>>(hmidg, row_of, hc);
    gemm_f<0, 1, 0, 0, 0><<<dim3(H_DIM / 128, T_TOK / 128, 1), blk, 0, stream>>>(
        hc, I_DIM, Wm2, I_DIM, 0L, T_TOK, H_DIM, I_DIM, H_DIM,
        out_final, nullptr, H_DIM, nullptr, nullptr, nullptr);
    gemm_f<0, 1, 1, 1, 0><<<dim3(2, 8, E_NUM), blk, 0, stream>>>(
        hmidg, I_DIM, dv2, I_DIM, (long)R_RANK * I_DIM, 0, R_RANK, I_DIM, RP,
        nullptr, t2g, RP, tok, seg, cnt);
    gemm_f<0, 0, 1, 1, 0><<<dim3(H_DIM / 128, 8, E_NUM), blk, 0, stream>>>(
        t2g, RP, du2b, RP, (long)H_DIM * RP, 0, H_DIM, RP, H_DIM,
        nullptr, deltab, H_DIM, tok, seg, cnt);
    finalfix_kernel<<<(int)(((long)T_TOK * H_DIM / 4 + 255) / 256), 256, 0, stream>>>(
        out_final, deltab, row_of);
  }
}

// Round 4
// 556.974 us; speedup vs baseline: 1.8950x; 1.0130x over previous
//
#include <hip/hip_runtime.h>

#define T_TOK 1024
#define H_DIM 2048
#define I_DIM 7168
#define E_NUM 8
#define R_RANK 159
#define RP 160
#define P_PAIRS 2048

typedef __attribute__((ext_vector_type(8))) short short8;
typedef __attribute__((ext_vector_type(4))) float f32x4;

__device__ __forceinline__ ushort f2b(float f) {
  uint u = __float_as_uint(f);
  uint r = (u + 0x7FFFu + ((u >> 16) & 1u)) >> 16;
  return (ushort)r;
}
__device__ __forceinline__ float b2f(ushort u) {
  return __uint_as_float(((uint)u) << 16);
}
__device__ __forceinline__ short8 pack8(float4 a, float4 b) {
  short8 o;
  o[0] = (short)f2b(a.x); o[1] = (short)f2b(a.y); o[2] = (short)f2b(a.z); o[3] = (short)f2b(a.w);
  o[4] = (short)f2b(b.x); o[5] = (short)f2b(b.y); o[6] = (short)f2b(b.z); o[7] = (short)f2b(b.w);
  return o;
}
__device__ __forceinline__ short8 zero8() {
  short8 z;
#pragma unroll
  for (int q = 0; q < 8; ++q) z[q] = 0;
  return z;
}

// ---------------- router ----------------
__global__ __launch_bounds__(256) void router_kernel(
    const float* __restrict__ x, const float* __restrict__ gw,
    float* __restrict__ logits, float* __restrict__ comb,
    int* __restrict__ sel_e, int* __restrict__ cnt) {
  int wave = threadIdx.x >> 6, lane = threadIdx.x & 63;
  int t = blockIdx.x * 4 + wave;
  const float* xr = x + (long)t * H_DIM;
  float acc[8] = {0.f,0.f,0.f,0.f,0.f,0.f,0.f,0.f};
  for (int h = lane * 4; h < H_DIM; h += 256) {
    const float4 xv = *(const float4*)&xr[h];
#pragma unroll
    for (int e = 0; e < 8; ++e) {
      const float4 gv = *(const float4*)&gw[e * H_DIM + h];
      acc[e] += xv.x * gv.x + xv.y * gv.y + xv.z * gv.z + xv.w * gv.w;
    }
  }
#pragma unroll
  for (int off = 32; off > 0; off >>= 1)
#pragma unroll
    for (int e = 0; e < 8; ++e) acc[e] += __shfl_down(acc[e], off);
  if (lane == 0) {
#pragma unroll
    for (int e = 0; e < 8; ++e) logits[(long)t * 8 + e] = acc[e];
    int i0 = 0;
    for (int e = 1; e < 8; ++e) if (acc[e] > acc[i0]) i0 = e;
    int i1 = (i0 == 0) ? 1 : 0;
    for (int e = 0; e < 8; ++e) if (e != i0 && acc[e] > acc[i1]) i1 = e;
    float ee = __expf(acc[i1] - acc[i0]);
    float w0 = 1.f / (1.f + ee), w1 = ee / (1.f + ee);
    for (int e = 0; e < 8; ++e) comb[t * 8 + e] = 0.f;
    comb[t * 8 + i0] = w0;
    comb[t * 8 + i1] = w1;
    sel_e[t * 2] = i0;
    sel_e[t * 2 + 1] = i1;
    atomicAdd(&cnt[i0], 1);
    atomicAdd(&cnt[i1], 1);
  }
}

__global__ void init_kernel(int* cnt, int* cursor) {
  int i = threadIdx.x;
  if (i < 8) { cnt[i] = 0; cursor[i] = 0; }
}

__global__ void scan_kernel(const int* cnt, int* seg) {
  if (threadIdx.x == 0) {
    int s = 0;
    for (int e = 0; e < 8; ++e) { seg[e] = s; s += cnt[e]; }
    seg[8] = s;
  }
}

__global__ void assign_kernel(const int* __restrict__ sel_e, const float* __restrict__ comb,
                              const int* __restrict__ seg, int* __restrict__ cursor,
                              int* __restrict__ tok, float* __restrict__ wrow,
                              int* __restrict__ row_of) {
  int t = blockIdx.x * blockDim.x + threadIdx.x;
  if (t >= T_TOK) return;
  for (int k = 0; k < 2; ++k) {
    int e = sel_e[t * 2 + k];
    int pos = atomicAdd(&cursor[e], 1);
    int row = seg[e] + pos;
    tok[row] = t;
    wrow[row] = comb[t * 8 + e];
    row_of[t * 2 + k] = row;
  }
}

// ---------------- casts ----------------
__global__ void cast8_kernel(const float* __restrict__ src, ushort* __restrict__ dst, long n8) {
  long idx = (long)blockIdx.x * blockDim.x + threadIdx.x;
  long stride = (long)gridDim.x * blockDim.x;
  for (long i = idx; i < n8; i += stride) {
    const float4 a = *(const float4*)&src[i * 8];
    const float4 b = *(const float4*)&src[i * 8 + 4];
    *(short8*)&dst[i * 8] = pack8(a, b);
  }
}

__global__ void padcast8_kernel(const float* __restrict__ src, ushort* __restrict__ dst, long rows) {
  long n8 = rows * (RP / 8);
  long idx = (long)blockIdx.x * blockDim.x + threadIdx.x;
  long stride = (long)gridDim.x * blockDim.x;
  for (long i = idx; i < n8; i += stride) {
    long row = i / (RP / 8);
    int c0 = (int)(i % (RP / 8)) * 8;
    short8 o;
#pragma unroll
    for (int j = 0; j < 8; ++j) {
      int c = c0 + j;
      o[j] = (c < R_RANK) ? (short)f2b(src[row * R_RANK + c]) : (short)0;
    }
    *(short8*)&dst[row * RP + c0] = o;
  }
}

// hc[t,i] = hmid[row0,i] + hmid[row1,i]   (bf16)
__global__ void hcomb_kernel(const ushort* __restrict__ hmid, const int* __restrict__ row_of,
                             ushort* __restrict__ hc) {
  long idx = (long)blockIdx.x * blockDim.x + threadIdx.x;
  long total = (long)T_TOK * I_DIM / 8;
  if (idx >= total) return;
  long i = idx * 8;
  int t = (int)(i / I_DIM);
  int col = (int)(i % I_DIM);
  int r0 = row_of[t * 2], r1 = row_of[t * 2 + 1];
  const short8 a = *(const short8*)&hmid[(long)r0 * I_DIM + col];
  const short8 b = *(const short8*)&hmid[(long)r1 * I_DIM + col];
  short8 o;
#pragma unroll
  for (int j = 0; j < 8; ++j)
    o[j] = (short)f2b(b2f((ushort)a[j]) + b2f((ushort)b[j]));
  *(short8*)&hc[i] = o;
}

// plan B: out[t,h] += delta[row0,h] + delta[row1,h]
__global__ void finalfix_kernel(float* __restrict__ out, const ushort* __restrict__ delta,
                                const int* __restrict__ row_of) {
  long idx = (long)blockIdx.x * blockDim.x + threadIdx.x;
  long total = (long)T_TOK * H_DIM / 4;
  if (idx >= total) return;
  long i = idx * 4;
  int t = (int)(i / H_DIM);
  int col = (int)(i % H_DIM);
  int r0 = row_of[t * 2], r1 = row_of[t * 2 + 1];
  float4 d = *(float4*)&out[i];
  d.x += b2f(delta[(long)r0 * H_DIM + col + 0]) + b2f(delta[(long)r1 * H_DIM + col + 0]);
  d.y += b2f(delta[(long)r0 * H_DIM + col + 1]) + b2f(delta[(long)r1 * H_DIM + col + 1]);
  d.z += b2f(delta[(long)r0 * H_DIM + col + 2]) + b2f(delta[(long)r1 * H_DIM + col + 2]);
  d.w += b2f(delta[(long)r0 * H_DIM + col + 3]) + b2f(delta[(long)r1 * H_DIM + col + 3]);
  *(float4*)&out[i] = d;
}

// plan A: out[t,h] = sum_{ks<4} dp[ks][t][h] + delta[row0,h] + delta[row1,h]
__global__ void finalfixA_kernel(float* __restrict__ out, const float* __restrict__ dp,
                                 const ushort* __restrict__ delta, const int* __restrict__ row_of) {
  long idx = (long)blockIdx.x * blockDim.x + threadIdx.x;
  long total = (long)T_TOK * H_DIM / 4;
  if (idx >= total) return;
  long i = idx * 4;
  int t = (int)(i / H_DIM);
  int col = (int)(i % H_DIM);
  int r0 = row_of[t * 2], r1 = row_of[t * 2 + 1];
  const long plane = (long)T_TOK * H_DIM;
  float4 s = *(const float4*)&dp[i];
#pragma unroll
  for (int k = 1; k < 4; ++k) {
    const float4 q = *(const float4*)&dp[k * plane + i];
    s.x += q.x; s.y += q.y; s.z += q.z; s.w += q.w;
  }
  s.x += b2f(delta[(long)r0 * H_DIM + col + 0]) + b2f(delta[(long)r1 * H_DIM + col + 0]);
  s.y += b2f(delta[(long)r0 * H_DIM + col + 1]) + b2f(delta[(long)r1 * H_DIM + col + 1]);
  s.z += b2f(delta[(long)r0 * H_DIM + col + 2]) + b2f(delta[(long)r1 * H_DIM + col + 2]);
  s.w += b2f(delta[(long)r0 * H_DIM + col + 3]) + b2f(delta[(long)r1 * H_DIM + col + 3]);
  *(float4*)&out[i] = s;
}

template <int KS>
__global__ void reduce_cast_kernel(const float* __restrict__ P, long plane,
                                   ushort* __restrict__ out, long n) {
  long i = (long)blockIdx.x * blockDim.x + threadIdx.x;
  if (i >= n) return;
  float s = 0.f;
#pragma unroll
  for (int k = 0; k < KS; ++k) s += P[(long)k * plane + i];
  out[i] = f2b(s);
}

// ---------------- general GEMM: C[M,N] = A[M,K] @ B[N,K]^T ----------------
// CBF16 path uses an LDS-transpose epilogue: swizzled scatter to LDS, then
// coalesced short8 row stores (epilogue VMEM ops 64 scalar -> 8 vector).
template <int AF32, int BF32, int CBF16, int PEREXP, int AMAP>
__global__ __launch_bounds__(256) void gemm_f(
    const void* __restrict__ Ap, int lda,
    const void* __restrict__ Bp, int ldb, long Bstride,
    int M, int N, int K, int Npad,
    float* __restrict__ Cf, ushort* __restrict__ Cb, int ldc,
    const int* __restrict__ tok, const int* __restrict__ seg, const int* __restrict__ cnt) {
  __shared__ ushort smem[16384];  // As(8KB) | Bs(8KB) | free 16KB ; epilogue aliases all 32KB
  ushort* As = smem;
  ushort* Bs = smem + 4096;
  const float* Af = (const float*)Ap;
  const ushort* Ab = (const ushort*)Ap;
  const float* Bf = (const float*)Bp;
  const ushort* Bb = (const ushort*)Bp;
  const int* amap = tok;
  if (PEREXP) {
    int e = blockIdx.z;
    int m0 = seg[e];
    M = cnt[e];
    if ((int)(blockIdx.y * 128) >= M) return;
    if (AMAP) {
      amap = tok + m0;
    } else {
      if (AF32) Af += (long)m0 * lda; else Ab += (long)m0 * lda;
    }
    if (BF32) Bf += (long)e * Bstride; else Bb += (long)e * Bstride;
    if (CBF16) Cb += (long)m0 * ldc; else Cf += (long)m0 * ldc;
  }
  const int tid = threadIdx.x;
  const int lane = tid & 63, wave = tid >> 6;
  const int wm = (wave >> 1) * 64, wn = (wave & 1) * 64;
  const int row0 = blockIdx.y * 128, col0 = blockIdx.x * 128;
  const int sub_r = tid >> 2;
  const int sub_c = (tid & 3) * 8;

  const float* afrow[2]; const ushort* abrow[2];
  const float* bfrow[2]; const ushort* bbrow[2];
#pragma unroll
  for (int p = 0; p < 2; ++p) {
    int r = row0 + p * 64 + sub_r; if (r > M - 1) r = M - 1;
    if (AMAP) r = amap[r];
    if (AF32) afrow[p] = Af + (long)r * lda + sub_c;
    else      abrow[p] = Ab + (long)r * lda + sub_c;
    int q = col0 + p * 64 + sub_r; if (q > N - 1) q = N - 1;
    if (BF32) bfrow[p] = Bf + (long)q * ldb + sub_c;
    else      bbrow[p] = Bb + (long)q * ldb + sub_c;
  }

  f32x4 acc[4][4] = {};

  for (int k0 = 0; k0 < K; k0 += 32) {
    float4 a0[2], a1[2], b0[2], b1[2];
    if (AF32) {
#pragma unroll
      for (int p = 0; p < 2; ++p) {
        a0[p] = *(const float4*)(afrow[p] + k0);
        a1[p] = *(const float4*)(afrow[p] + k0 + 4);
      }
    }
    if (BF32) {
#pragma unroll
      for (int p = 0; p < 2; ++p) {
        b0[p] = *(const float4*)(bfrow[p] + k0);
        b1[p] = *(const float4*)(bfrow[p] + k0 + 4);
      }
    }
    __syncthreads();
#pragma unroll
    for (int p = 0; p < 2; ++p) {
      if (AF32) {
        *(short8*)&As[(p * 256 + tid) * 8] = pack8(a0[p], a1[p]);
      } else {
        __builtin_amdgcn_global_load_lds((const __attribute__((address_space(1))) void*)(abrow[p] + k0),
                                         (__attribute__((address_space(3))) void*)&As[(p * 256 + tid) * 8],
                                         16, 0, 0);
      }
      if (BF32) {
        *(short8*)&Bs[(p * 256 + tid) * 8] = pack8(b0[p], b1[p]);
      } else {
        __builtin_amdgcn_global_load_lds((const __attribute__((address_space(1))) void*)(bbrow[p] + k0),
                                         (__attribute__((address_space(3))) void*)&Bs[(p * 256 + tid) * 8],
                                         16, 0, 0);
      }
    }
    __syncthreads();

    short8 av[4], bv[4];
#pragma unroll
    for (int mi = 0; mi < 4; ++mi)
      av[mi] = *(const short8*)&As[(wm + mi * 16 + (lane & 15)) * 32 + (lane >> 4) * 8];
#pragma unroll
    for (int ni = 0; ni < 4; ++ni)
      bv[ni] = *(const short8*)&Bs[(wn + ni * 16 + (lane & 15)) * 32 + (lane >> 4) * 8];
#pragma unroll
    for (int mi = 0; mi < 4; ++mi)
#pragma unroll
      for (int ni = 0; ni < 4; ++ni)
        acc[mi][ni] = __builtin_amdgcn_mfma_f32_16x16x32_bf16(av[mi], bv[ni], acc[mi][ni], 0, 0, 0);
  }

  const int er = (lane >> 4) * 4;
  const int ec = lane & 15;
  if (CBF16) {
    __syncthreads();
    ushort* Cs = smem;  // 128x128 bf16, XOR-swizzled rows (G4: 256B-row fix)
#pragma unroll
    for (int mi = 0; mi < 4; ++mi)
#pragma unroll
      for (int ni = 0; ni < 4; ++ni)
#pragma unroll
        for (int j = 0; j < 4; ++j) {
          int rr = wm + mi * 16 + er + j;
          int c = wn + ni * 16 + ec;
          Cs[rr * 128 + (c ^ ((rr & 7) << 3))] =
              (col0 + c < N) ? f2b(acc[mi][ni][j]) : (ushort)0;
        }
    __syncthreads();
    const int rl = tid >> 1;
    const int clb = (tid & 1) * 64;
    const int r = row0 + rl;
    if (r < M) {
      const int k8 = (rl & 7) << 3;
#pragma unroll
      for (int jj = 0; jj < 8; ++jj) {
        int cg = col0 + clb + jj * 8;
        if (cg < Npad) {
          short8 v = *(const short8*)&Cs[rl * 128 + ((clb + jj * 8) ^ k8)];
          *(short8*)&Cb[(long)r * ldc + cg] = v;
        }
      }
    }
  } else {
#pragma unroll
    for (int mi = 0; mi < 4; ++mi)
#pragma unroll
      for (int ni = 0; ni < 4; ++ni)
#pragma unroll
        for (int j = 0; j < 4; ++j) {
          int r = row0 + wm + mi * 16 + er + j;
          int c = col0 + wn + ni * 16 + ec;
          if (r < M && c < Npad)
            Cf[(long)r * ldc + c] = (c < N) ? acc[mi][ni][j] : 0.f;
        }
  }
}

// ---------------- split-K GEMM (bf16 in, f32 partials) ----------------
template <int PEREXP, int KS>
__global__ __launch_bounds__(256) void gemm_splitk(
    const ushort* __restrict__ A, int lda,
    const ushort* __restrict__ B, int ldb, long Bstride,
    int M, int N, int Npad, int kchunk,
    float* __restrict__ P, int ldc, long Pplane,
    const int* __restrict__ seg, const int* __restrict__ cnt) {
  __shared__ ushort As[128 * 32];
  __shared__ ushort Bs[128 * 32];
  int ks;
  if (PEREXP) {
    int e = blockIdx.z / KS;
    ks = blockIdx.z % KS;
    int m0 = seg[e];
    M = cnt[e];
    if ((int)(blockIdx.y * 128) >= M) return;
    A += (long)m0 * lda;
    B += (long)e * Bstride;
    P += (long)m0 * ldc;
  } else {
    ks = blockIdx.z;
  }
  P += (long)ks * Pplane;
  const int kbase = ks * kchunk;

  const int tid = threadIdx.x;
  const int lane = tid & 63, wave = tid >> 6;
  const int wm = (wave >> 1) * 64, wn = (wave & 1) * 64;
  const int row0 = blockIdx.y * 128, col0 = blockIdx.x * 128;
  const int sub_r = tid >> 2;
  const int sub_c = (tid & 3) * 8;

  const ushort *ar[2], *br[2];
#pragma unroll
  for (int p = 0; p < 2; ++p) {
    int r = row0 + p * 64 + sub_r; if (r > M - 1) r = M - 1;
    ar[p] = A + (long)r * lda + kbase + sub_c;
    int q = col0 + p * 64 + sub_r; if (q > N - 1) q = N - 1;
    br[p] = B + (long)q * ldb + kbase + sub_c;
  }

  f32x4 acc[4][4] = {};

  for (int kk = 0; kk < kchunk; kk += 32) {
    __syncthreads();
#pragma unroll
    for (int p = 0; p < 2; ++p) {
      __builtin_amdgcn_global_load_lds((const __attribute__((address_space(1))) void*)(ar[p] + kk),
                                       (__attribute__((address_space(3))) void*)&As[(p * 256 + tid) * 8], 16, 0, 0);
      __builtin_amdgcn_global_load_lds((const __attribute__((address_space(1))) void*)(br[p] + kk),
                                       (__attribute__((address_space(3))) void*)&Bs[(p * 256 + tid) * 8], 16, 0, 0);
    }
    __syncthreads();

    short8 av[4], bv[4];
#pragma unroll
    for (int mi = 0; mi < 4; ++mi)
      av[mi] = *(const short8*)&As[(wm + mi * 16 + (lane & 15)) * 32 + (lane >> 4) * 8];
#pragma unroll
    for (int ni = 0; ni < 4; ++ni)
      bv[ni] = *(const short8*)&Bs[(wn + ni * 16 + (lane & 15)) * 32 + (lane >> 4) * 8];
#pragma unroll
    for (int mi = 0; mi < 4; ++mi)
#pragma unroll
      for (int ni = 0; ni < 4; ++ni)
        acc[mi][ni] = __builtin_amdgcn_mfma_f32_16x16x32_bf16(av[mi], bv[ni], acc[mi][ni], 0, 0, 0);
  }

  const int er = (lane >> 4) * 4;
  const int ec = lane & 15;
#pragma unroll
  for (int mi = 0; mi < 4; ++mi)
#pragma unroll
    for (int ni = 0; ni < 4; ++ni)
#pragma unroll
      for (int j = 0; j < 4; ++j) {
        int r = row0 + wm + mi * 16 + er + j;
        int c = col0 + wn + ni * 16 + ec;
        if (r < M && c < Npad)
          P[(long)r * ldc + c] = (c < N) ? acc[mi][ni][j] : 0.f;
      }
}

// ---------------- fused dual-B split-K8 GEMM for t1/t3 ----------------
__global__ __launch_bounds__(256) void gemm_t13(
    const ushort* __restrict__ xb, const ushort* __restrict__ dv1b,
    const ushort* __restrict__ dv3b, const int* __restrict__ tok,
    const int* __restrict__ seg, const int* __restrict__ cnt,
    float* __restrict__ p1, float* __restrict__ p3) {
  __shared__ ushort As[128 * 32], Bs1[128 * 32], Bs3[128 * 32];
  const int e = blockIdx.z >> 3;
  const int ks = blockIdx.z & 7;
  const int m0 = seg[e], M = cnt[e];
  const int row0 = blockIdx.y * 128, col0 = blockIdx.x * 128;
  if (row0 >= M) return;
  const int kbase = ks * 256;

  const int tid = threadIdx.x;
  const int lane = tid & 63, wave = tid >> 6;
  const int wm = (wave >> 1) * 64, wn = (wave & 1) * 64;
  const int sub_r = tid >> 2;
  const int sub_c = (tid & 3) * 8;

  const ushort *ar[2], *b1r[2], *b3r[2];
#pragma unroll
  for (int p = 0; p < 2; ++p) {
    int r = row0 + p * 64 + sub_r; if (r > M - 1) r = M - 1;
    int t = tok[m0 + r];
    ar[p] = xb + (long)t * H_DIM + kbase + sub_c;
    int q = col0 + p * 64 + sub_r; if (q > R_RANK - 1) q = R_RANK - 1;
    b1r[p] = dv1b + (long)e * R_RANK * H_DIM + (long)q * H_DIM + kbase + sub_c;
    b3r[p] = dv3b + (long)e * R_RANK * H_DIM + (long)q * H_DIM + kbase + sub_c;
  }

  f32x4 acc1[4][4] = {}, acc3[4][4] = {};

  for (int kk = 0; kk < 256; kk += 32) {
    __syncthreads();
#pragma unroll
    for (int p = 0; p < 2; ++p) {
      __builtin_amdgcn_global_load_lds((const __attribute__((address_space(1))) void*)(ar[p] + kk),
                                       (__attribute__((address_space(3))) void*)&As[(p * 256 + tid) * 8], 16, 0, 0);
      __builtin_amdgcn_global_load_lds((const __attribute__((address_space(1))) void*)(b1r[p] + kk),
                                       (__attribute__((address_space(3))) void*)&Bs1[(p * 256 + tid) * 8], 16, 0, 0);
      __builtin_amdgcn_global_load_lds((const __attribute__((address_space(1))) void*)(b3r[p] + kk),
                                       (__attribute__((address_space(3))) void*)&Bs3[(p * 256 + tid) * 8], 16, 0, 0);
    }
    __syncthreads();

    short8 av[4], bv1[4], bv3[4];
#pragma unroll
    for (int mi = 0; mi < 4; ++mi)
      av[mi] = *(const short8*)&As[(wm + mi * 16 + (lane & 15)) * 32 + (lane >> 4) * 8];
#pragma unroll
    for (int ni = 0; ni < 4; ++ni) {
      bv1[ni] = *(const short8*)&Bs1[(wn + ni * 16 + (lane & 15)) * 32 + (lane >> 4) * 8];
      bv3[ni] = *(const short8*)&Bs3[(wn + ni * 16 + (lane & 15)) * 32 + (lane >> 4) * 8];
    }
#pragma unroll
    for (int mi = 0; mi < 4; ++mi)
#pragma unroll
      for (int ni = 0; ni < 4; ++ni) {
        acc1[mi][ni] = __builtin_amdgcn_mfma_f32_16x16x32_bf16(av[mi], bv1[ni], acc1[mi][ni], 0, 0, 0);
        acc3[mi][ni] = __builtin_amdgcn_mfma_f32_16x16x32_bf16(av[mi], bv3[ni], acc3[mi][ni], 0, 0, 0);
      }
  }

  const int er = (lane >> 4) * 4;
  const int ec = lane & 15;
  const long plane = (long)P_PAIRS * RP;
#pragma unroll
  for (int mi = 0; mi < 4; ++mi)
#pragma unroll
    for (int ni = 0; ni < 4; ++ni)
#pragma unroll
      for (int j = 0; j < 4; ++j) {
        int r = row0 + wm + mi * 16 + er + j;
        int c = col0 + wn + ni * 16 + ec;
        if (r < M && c < RP) {
          long o = (long)ks * plane + (long)(m0 + r) * RP + c;
          p1[o] = (c < R_RANK) ? acc1[mi][ni][j] : 0.f;
          p3[o] = (c < R_RANK) ? acc3[mi][ni][j] : 0.f;
        }
      }
}

// ---------------- fused dual GEMM: gate/up expansion + silu + weight ----------------
// Epilogue: two-phase LDS transpose (gate then up); bias reads become
// row-indirect but column-coalesced short8 loads; hmid stores coalesced short8.
__global__ __launch_bounds__(256) void gemm_hmid(
    const ushort* __restrict__ t1g, const ushort* __restrict__ t3g,
    const ushort* __restrict__ du1b, const ushort* __restrict__ du3b,
    const ushort* __restrict__ bgate, const ushort* __restrict__ bup,
    const int* __restrict__ tok, const float* __restrict__ wrow,
    const int* __restrict__ seg, const int* __restrict__ cnt,
    ushort* __restrict__ hmid) {
  __shared__ ushort smem[16384];  // As1|As3|Bs1|Bs3 (4x8KB); epilogue aliases all 32KB
  ushort* As1 = smem;
  ushort* As3 = smem + 4096;
  ushort* Bs1 = smem + 8192;
  ushort* Bs3 = smem + 12288;
  int e = blockIdx.z;
  int m0 = seg[e], M = cnt[e];
  if ((int)(blockIdx.y * 128) >= M) return;
  const ushort* A1 = t1g + (long)m0 * RP;
  const ushort* A3 = t3g + (long)m0 * RP;
  const ushort* B1 = du1b + (long)e * I_DIM * RP;
  const ushort* B3 = du3b + (long)e * I_DIM * RP;
  tok += m0; wrow += m0;
  ushort* H = hmid + (long)m0 * I_DIM;

  const int tid = threadIdx.x;
  const int lane = tid & 63, wave = tid >> 6;
  const int wm = (wave >> 1) * 64, wn = (wave & 1) * 64;
  const int row0 = blockIdx.y * 128, col0 = blockIdx.x * 128;
  const int sub_r = tid >> 2;
  const int sub_c = (tid & 3) * 8;

  const ushort *a1r[2], *a3r[2], *b1r[2], *b3r[2];
#pragma unroll
  for (int p = 0; p < 2; ++p) {
    int r = row0 + p * 64 + sub_r; if (r > M - 1) r = M - 1;
    a1r[p] = A1 + (long)r * RP + sub_c;
    a3r[p] = A3 + (long)r * RP + sub_c;
    int q = col0 + p * 64 + sub_r; if (q > I_DIM - 1) q = I_DIM - 1;
    b1r[p] = B1 + (long)q * RP + sub_c;
    b3r[p] = B3 + (long)q * RP + sub_c;
  }

  f32x4 acc1[4][4] = {}, acc3[4][4] = {};

  for (int k0 = 0; k0 < RP; k0 += 32) {
    __syncthreads();
#pragma unroll
    for (int p = 0; p < 2; ++p) {
      __builtin_amdgcn_global_load_lds((const __attribute__((address_space(1))) void*)(a1r[p] + k0),
                                       (__attribute__((address_space(3))) void*)&As1[(p * 256 + tid) * 8], 16, 0, 0);
      __builtin_amdgcn_global_load_lds((const __attribute__((address_space(1))) void*)(a3r[p] + k0),
                                       (__attribute__((address_space(3))) void*)&As3[(p * 256 + tid) * 8], 16, 0, 0);
      __builtin_amdgcn_global_load_lds((const __attribute__((address_space(1))) void*)(b1r[p] + k0),
                                       (__attribute__((address_space(3))) void*)&Bs1[(p * 256 + tid) * 8], 16, 0, 0);
      __builtin_amdgcn_global_load_lds((const __attribute__((address_space(1))) void*)(b3r[p] + k0),
                                       (__attribute__((address_space(3))) void*)&Bs3[(p * 256 + tid) * 8], 16, 0, 0);
    }
    __syncthreads();

    short8 av1[4], av3[4], bv1[4], bv3[4];
#pragma unroll
    for (int mi = 0; mi < 4; ++mi) {
      av1[mi] = *(const short8*)&As1[(wm + mi * 16 + (lane & 15)) * 32 + (lane >> 4) * 8];
      av3[mi] = *(const short8*)&As3[(wm + mi * 16 + (lane & 15)) * 32 + (lane >> 4) * 8];
    }
#pragma unroll
    for (int ni = 0; ni < 4; ++ni) {
      bv1[ni] = *(const short8*)&Bs1[(wn + ni * 16 + (lane & 15)) * 32 + (lane >> 4) * 8];
      bv3[ni] = *(const short8*)&Bs3[(wn + ni * 16 + (lane & 15)) * 32 + (lane >> 4) * 8];
    }
#pragma unroll
    for (int mi = 0; mi < 4; ++mi)
#pragma unroll
      for (int ni = 0; ni < 4; ++ni) {
        acc1[mi][ni] = __builtin_amdgcn_mfma_f32_16x16x32_bf16(av1[mi], bv1[ni], acc1[mi][ni], 0, 0, 0);
        acc3[mi][ni] = __builtin_amdgcn_mfma_f32_16x16x32_bf16(av3[mi], bv3[ni], acc3[mi][ni], 0, 0, 0);
      }
  }

  const int er = (lane >> 4) * 4;
  const int ec = lane & 15;
  __syncthreads();
  ushort* Cs = smem;  // 128x128 bf16 swizzled
  // ---- phase 1: gate ----
#pragma unroll
  for (int mi = 0; mi < 4; ++mi)
#pragma unroll
    for (int ni = 0; ni < 4; ++ni)
#pragma unroll
      for (int j = 0; j < 4; ++j) {
        int rr = wm + mi * 16 + er + j;
        int c = wn + ni * 16 + ec;
        Cs[rr * 128 + (c ^ ((rr & 7) << 3))] = f2b(acc1[mi][ni][j]);
      }
  __syncthreads();
  const int rl = tid >> 1;
  const int clb = (tid & 1) * 64;
  const int r = row0 + rl;
  const bool rok = (r < M);
  const int t = rok ? tok[r] : 0;
  const float w = rok ? wrow[r] : 0.f;
  const int k8 = (rl & 7) << 3;
  uint svp[32];  // silu values, packed 2x bf16
#pragma unroll
  for (int jj = 0; jj < 8; ++jj) {
    short8 gb = zero8();
    if (rok) gb = *(const short8*)&bgate[(long)t * I_DIM + col0 + clb + jj * 8];
    short8 gv = *(const short8*)&Cs[rl * 128 + ((clb + jj * 8) ^ k8)];
#pragma unroll
    for (int q = 0; q < 8; q += 2) {
      float g0 = b2f((ushort)gv[q]) + b2f((ushort)gb[q]);
      float g1 = b2f((ushort)gv[q + 1]) + b2f((ushort)gb[q + 1]);
      float s0 = g0 / (1.f + __expf(-g0));
      float s1 = g1 / (1.f + __expf(-g1));
      svp[jj * 4 + q / 2] = (uint)f2b(s0) | ((uint)f2b(s1) << 16);
    }
  }
  __syncthreads();
  // ---- phase 2: up ----
#pragma unroll
  for (int mi = 0; mi < 4; ++mi)
#pragma unroll
    for (int ni = 0; ni < 4; ++ni)
#pragma unroll
      for (int j = 0; j < 4; ++j) {
        int rr = wm + mi * 16 + er + j;
        int c = wn + ni * 16 + ec;
        Cs[rr * 128 + (c ^ ((rr & 7) << 3))] = f2b(acc3[mi][ni][j]);
      }
  __syncthreads();
#pragma unroll
  for (int jj = 0; jj < 8; ++jj) {
    short8 ub = zero8();
    if (rok) ub = *(const short8*)&bup[(long)t * I_DIM + col0 + clb + jj * 8];
    short8 uv = *(const short8*)&Cs[rl * 128 + ((clb + jj * 8) ^ k8)];
    short8 o;
#pragma unroll
    for (int q = 0; q < 8; q += 2) {
      uint sp = svp[jj * 4 + q / 2];
      float u0 = b2f((ushort)uv[q]) + b2f((ushort)ub[q]);
      float u1 = b2f((ushort)uv[q + 1]) + b2f((ushort)ub[q + 1]);
      o[q]     = (short)f2b(w * b2f((ushort)(sp & 0xFFFFu)) * u0);
      o[q + 1] = (short)f2b(w * b2f((ushort)(sp >> 16)) * u1);
    }
    if (rok) *(short8*)&H[(long)r * I_DIM + col0 + clb + jj * 8] = o;
  }
}

// ---------------- launch ----------------
extern "C" void kernel_launch(void* const* d_in, const int* in_sizes, int n_in,
                              void* d_out, int out_size, void* d_ws, size_t ws_size,
                              hipStream_t stream) {
  const float* x   = (const float*)d_in[0];
  const float* gw  = (const float*)d_in[1];
  const float* Wm1 = (const float*)d_in[2];
  const float* Wm2 = (const float*)d_in[3];
  const float* Wm3 = (const float*)d_in[4];
  const float* du1 = (const float*)d_in[5];
  const float* dv1 = (const float*)d_in[6];
  const float* du2 = (const float*)d_in[7];
  const float* dv2 = (const float*)d_in[8];
  const float* du3 = (const float*)d_in[9];
  const float* dv3 = (const float*)d_in[10];

  float* out_final  = (float*)d_out;
  float* out_logits = out_final + (long)T_TOK * H_DIM;

  char* p = (char*)d_ws;
  auto alloc = [&](size_t bytes) {
    char* r = p;
    p += (bytes + 255) & ~(size_t)255;
    return r;
  };

  float* comb   = (float*)alloc((size_t)T_TOK * E_NUM * 4);
  float* wrow   = (float*)alloc((size_t)P_PAIRS * 4);
  int* cnt      = (int*)alloc(64);
  int* cursor   = (int*)alloc(64);
  int* seg      = (int*)alloc(64);
  int* sel_e    = (int*)alloc((size_t)T_TOK * 2 * 4);
  int* tok      = (int*)alloc((size_t)P_PAIRS * 4);
  int* row_of   = (int*)alloc((size_t)T_TOK * 2 * 4);
  ushort* bgate_b = (ushort*)alloc((size_t)T_TOK * I_DIM * 2);
  ushort* bup_b   = (ushort*)alloc((size_t)T_TOK * I_DIM * 2);
  ushort* hmidg   = (ushort*)alloc((size_t)P_PAIRS * I_DIM * 2);
  ushort* t1g     = (ushort*)alloc((size_t)P_PAIRS * RP * 2);
  ushort* t3g     = (ushort*)alloc((size_t)P_PAIRS * RP * 2);
  ushort* t2g     = (ushort*)alloc((size_t)P_PAIRS * RP * 2);
  ushort* du1b    = (ushort*)alloc((size_t)E_NUM * I_DIM * RP * 2);
  ushort* du3b    = (ushort*)alloc((size_t)E_NUM * I_DIM * RP * 2);
  ushort* du2b    = (ushort*)alloc((size_t)E_NUM * H_DIM * RP * 2);
  size_t needed_B = (size_t)(p - (char*)d_ws);
  ushort* xb   = (ushort*)alloc((size_t)T_TOK * H_DIM * 2);
  ushort* w1b  = (ushort*)alloc((size_t)I_DIM * H_DIM * 2);
  ushort* w3b  = (ushort*)alloc((size_t)I_DIM * H_DIM * 2);
  ushort* dv1b = (ushort*)alloc((size_t)E_NUM * R_RANK * H_DIM * 2);
  ushort* dv3b = (ushort*)alloc((size_t)E_NUM * R_RANK * H_DIM * 2);
  size_t needed_A = (size_t)(p - (char*)d_ws);

  ushort* hc     = bgate_b;
  ushort* deltab = bup_b;

  if (ws_size < needed_B) return;
  const bool planA = (ws_size >= needed_A);

  dim3 blk(256);

  init_kernel<<<1, 64, 0, stream>>>(cnt, cursor);
  router_kernel<<<T_TOK / 4, 256, 0, stream>>>(x, gw, out_logits, comb, sel_e, cnt);
  scan_kernel<<<1, 64, 0, stream>>>(cnt, seg);
  assign_kernel<<<4, 256, 0, stream>>>(sel_e, comb, seg, cursor, tok, wrow, row_of);

  padcast8_kernel<<<4480, 256, 0, stream>>>(du1, du1b, (long)E_NUM * I_DIM);
  padcast8_kernel<<<4480, 256, 0, stream>>>(du3, du3b, (long)E_NUM * I_DIM);
  padcast8_kernel<<<1280, 256, 0, stream>>>(du2, du2b, (long)E_NUM * H_DIM);

  if (planA) {
    cast8_kernel<<<1024, 256, 0, stream>>>(x, xb, (long)T_TOK * H_DIM / 8);
    cast8_kernel<<<7168, 256, 0, stream>>>(Wm1, w1b, (long)I_DIM * H_DIM / 8);
    cast8_kernel<<<7168, 256, 0, stream>>>(Wm3, w3b, (long)I_DIM * H_DIM / 8);
    cast8_kernel<<<1272, 256, 0, stream>>>(dv1, dv1b, (long)E_NUM * R_RANK * H_DIM / 8);
    cast8_kernel<<<1272, 256, 0, stream>>>(dv3, dv3b, (long)E_NUM * R_RANK * H_DIM / 8);

    gemm_f<0, 0, 1, 0, 0><<<dim3(I_DIM / 128, T_TOK / 128, 1), blk, 0, stream>>>(
        xb, H_DIM, w1b, H_DIM, 0L, T_TOK, I_DIM, H_DIM, I_DIM,
        nullptr, bgate_b, I_DIM, nullptr, nullptr, nullptr);
    gemm_f<0, 0, 1, 0, 0><<<dim3(I_DIM / 128, T_TOK / 128, 1), blk, 0, stream>>>(
        xb, H_DIM, w3b, H_DIM, 0L, T_TOK, I_DIM, H_DIM, I_DIM,
        nullptr, bup_b, I_DIM, nullptr, nullptr, nullptr);

    ushort* w2b  = w1b;
    ushort* dv2b = w3b;
    cast8_kernel<<<7168, 256, 0, stream>>>(Wm2, w2b, (long)I_DIM * H_DIM / 8);
    cast8_kernel<<<4452, 256, 0, stream>>>(dv2, dv2b, (long)E_NUM * R_RANK * I_DIM / 8);

    float* p1 = (float*)hmidg;
    float* p3 = p1 + (long)8 * P_PAIRS * RP;
    gemm_t13<<<dim3(2, 8, 64), blk, 0, stream>>>(xb, dv1b, dv3b, tok, seg, cnt, p1, p3);
    reduce_cast_kernel<8><<<1280, 256, 0, stream>>>(p1, (long)P_PAIRS * RP, t1g, (long)P_PAIRS * RP);
    reduce_cast_kernel<8><<<1280, 256, 0, stream>>>(p3, (long)P_PAIRS * RP, t3g, (long)P_PAIRS * RP);

    gemm_hmid<<<dim3(I_DIM / 128, 8, E_NUM), blk, 0, stream>>>(
        t1g, t3g, du1b, du3b, bgate_b, bup_b, tok, wrow, seg, cnt, hmidg);

    hcomb_kernel<<<(int)(((long)T_TOK * I_DIM / 8 + 255) / 256), 256, 0, stream>>>(hmidg, row_of, hc);

    float* dp = (float*)du1b;
    gemm_splitk<0, 4><<<dim3(H_DIM / 128, T_TOK / 128, 4), blk, 0, stream>>>(
        hc, I_DIM, w2b, I_DIM, 0L, T_TOK, H_DIM, H_DIM, I_DIM / 4,
        dp, H_DIM, (long)T_TOK * H_DIM, nullptr, nullptr);

    float* p2 = (float*)bgate_b;
    gemm_splitk<1, 8><<<dim3(2, 8, 64), blk, 0, stream>>>(
        hmidg, I_DIM, dv2b, I_DIM, (long)R_RANK * I_DIM, 0, R_RANK, RP, I_DIM / 8,
        p2, RP, (long)P_PAIRS * RP, seg, cnt);
    reduce_cast_kernel<8><<<1280, 256, 0, stream>>>(p2, (long)P_PAIRS * RP, t2g, (long)P_PAIRS * RP);

    gemm_f<0, 0, 1, 1, 0><<<dim3(H_DIM / 128, 8, E_NUM), blk, 0, stream>>>(
        t2g, RP, du2b, RP, (long)H_DIM * RP, 0, H_DIM, RP, H_DIM,
        nullptr, deltab, H_DIM, tok, seg, cnt);

    finalfixA_kernel<<<2048, 256, 0, stream>>>(out_final, dp, deltab, row_of);
  } else {
    gemm_f<1, 1, 1, 0, 0><<<dim3(I_DIM / 128, T_TOK / 128, 1), blk, 0, stream>>>(
        x, H_DIM, Wm1, H_DIM, 0L, T_TOK, I_DIM, H_DIM, I_DIM,
        nullptr, bgate_b, I_DIM, nullptr, nullptr, nullptr);
    gemm_f<1, 1, 1, 0, 0><<<dim3(I_DIM / 128, T_TOK / 128, 1), blk, 0, stream>>>(
        x, H_DIM, Wm3, H_DIM, 0L, T_TOK, I_DIM, H_DIM, I_DIM,
        nullptr, bup_b, I_DIM, nullptr, nullptr, nullptr);
    gemm_f<1, 1, 1, 1, 1><<<dim3(2, 8, E_NUM), blk, 0, stream>>>(
        x, H_DIM, dv1, H_DIM, (long)R_RANK * H_DIM, 0, R_RANK, H_DIM, RP,
        nullptr, t1g, RP, tok, seg, cnt);
    gemm_f<1, 1, 1, 1, 1><<<dim3(2, 8, E_NUM), blk, 0, stream>>>(
        x, H_DIM, dv3, H_DIM, (long)R_RANK * H_DIM, 0, R_RANK, H_DIM, RP,
        nullptr, t3g, RP, tok, seg, cnt);
    gemm_hmid<<<dim3(I_DIM / 128, 8, E_NUM), blk, 0, stream>>>(
        t1g, t3g, du1b, du3b, bgate_b, bup_b, tok, wrow, seg, cnt, hmidg);
    hcomb_kernel<<<(int)(((long)T_TOK * I_DIM / 8 + 255) / 256), 256, 0, stream>>>(hmidg, row_of, hc);
    gemm_f<0, 1, 0, 0, 0><<<dim3(H_DIM / 128, T_TOK / 128, 1), blk, 0, stream>>>(
        hc, I_DIM, Wm2, I_DIM, 0L, T_TOK, H_DIM, I_DIM, H_DIM,
        out_final, nullptr, H_DIM, nullptr, nullptr, nullptr);
    gemm_f<0, 1, 1, 1, 0><<<dim3(2, 8, E_NUM), blk, 0, stream>>>(
        hmidg, I_DIM, dv2, I_DIM, (long)R_RANK * I_DIM, 0, R_RANK, I_DIM, RP,
        nullptr, t2g, RP, tok, seg, cnt);
    gemm_f<0, 0, 1, 1, 0><<<dim3(H_DIM / 128, 8, E_NUM), blk, 0, stream>>>(
        t2g, RP, du2b, RP, (long)H_DIM * RP, 0, H_DIM, RP, H_DIM,
        nullptr, deltab, H_DIM, tok, seg, cnt);
    finalfix_kernel<<<(int)(((long)T_TOK * H_DIM / 4 + 255) / 256), 256, 0, stream>>>(
        out_final, deltab, row_of);
  }
}